// Round 7
// baseline (431.447 us; speedup 1.0000x reference)
//
#include <hip/hip_runtime.h>

#define DIM    768
#define HEADS  12
#define HD     64
#define BB     4
#define PP     2048
#define MTOT   8192   /* BB*PP */
#define NQKV   2304
#define QBLK   128

typedef unsigned short bf16s;                                   // bf16 storage
typedef short bf16x8 __attribute__((ext_vector_type(8)));       // MFMA A/B frag
typedef float f32x4  __attribute__((ext_vector_type(4)));       // MFMA C/D frag

__device__ __forceinline__ bf16s f2bf(float f) {
    unsigned int u = __float_as_uint(f);
    unsigned int r = u + 0x7fffu + ((u >> 16) & 1u);            // RNE
    return (bf16s)(r >> 16);
}
__device__ __forceinline__ float bf2f(bf16s s) {
    return __uint_as_float(((unsigned int)s) << 16);
}
__device__ __forceinline__ float exp2g(float x) {
    return __builtin_amdgcn_exp2f(x);                           // v_exp_f32
}
__device__ __forceinline__ unsigned cvt_pk_bf16(float a, float b) {
    unsigned r;
    asm("v_cvt_pk_bf16_f32 %0, %1, %2" : "=v"(r) : "v"(a), "v"(b));
    return r;                                                   // lo=bf16(a), hi=bf16(b)
}

// ---------------------------------------------------------------- LayerNorm
__global__ __launch_bounds__(256) void ln_kernel(
        const float* __restrict__ x, const float* __restrict__ w,
        const float* __restrict__ b, bf16s* __restrict__ xn) {
    int row = blockIdx.x;
    const float* xr = x + (size_t)row * DIM;
    int t = threadIdx.x;
    float v0 = xr[t], v1 = xr[t + 256], v2 = xr[t + 512];
    float s  = v0 + v1 + v2;
    float ss = v0*v0 + v1*v1 + v2*v2;
    for (int off = 32; off; off >>= 1) {
        s  += __shfl_down(s, off);
        ss += __shfl_down(ss, off);
    }
    __shared__ float red[8];
    int wid = t >> 6, lane = t & 63;
    if (lane == 0) { red[wid] = s; red[4 + wid] = ss; }
    __syncthreads();
    if (t == 0) {
        float S  = red[0] + red[1] + red[2] + red[3];
        float SS = red[4] + red[5] + red[6] + red[7];
        float mean = S * (1.0f / DIM);
        float var  = SS * (1.0f / DIM) - mean * mean;
        red[0] = mean;
        red[1] = rsqrtf(var + 1e-5f);
    }
    __syncthreads();
    float mean = red[0], inv = red[1];
    bf16s* xo = xn + (size_t)row * DIM;
    xo[t]       = f2bf((v0 - mean) * inv * w[t]       + b[t]);
    xo[t + 256] = f2bf((v1 - mean) * inv * w[t + 256] + b[t + 256]);
    xo[t + 512] = f2bf((v2 - mean) * inv * w[t + 512] + b[t + 512]);
}

// ------------------------------------------------- transpose + cast weights
// dst[n][k] = src[k][n] * scale
template<bool LO>
__global__ __launch_bounds__(256) void transpose_cast(
        const float* __restrict__ src, bf16s* __restrict__ dst,
        bf16s* __restrict__ dst_lo, int Kdim, int Ndim, float scale) {
    __shared__ float tile[32][33];
    int n0 = blockIdx.x * 32, k0 = blockIdx.y * 32;
    int tx = threadIdx.x, ty = threadIdx.y;
    #pragma unroll
    for (int i = 0; i < 4; ++i)
        tile[ty + 8*i][tx] = src[(size_t)(k0 + ty + 8*i) * Ndim + n0 + tx];
    __syncthreads();
    #pragma unroll
    for (int i = 0; i < 4; ++i) {
        float v = tile[tx][ty + 8*i] * scale;
        size_t oidx = (size_t)(n0 + ty + 8*i) * Kdim + k0 + tx;
        bf16s hi = f2bf(v);
        dst[oidx] = hi;
        if (LO) dst_lo[oidx] = f2bf(v - bf2f(hi));
    }
}

// ----------------------------------------------------------------- GEMM
// C[M x N] = A[M x 768(K)] @ Bt[N x 768]^T ; 128x128 tile, 4 waves (2x2 of 64x64)
// MODE 0: N=2304 -> Q(prescaled) [b,h,p,d], K [b,h,p,d], V^T [b,h,d,p] (+bv)
// MODE 1: N=768, K'=3*768 (Ah*Bh + Ah*Bl + Al*Bh), out fp32 + bfc
template<int MODE>
__global__ __launch_bounds__(256) void gemm_bt(
        const bf16s* __restrict__ A0, const bf16s* __restrict__ A1,
        const bf16s* __restrict__ B0, const bf16s* __restrict__ B1,
        const float* __restrict__ bias,
        bf16s* __restrict__ Qo, bf16s* __restrict__ Ko, bf16s* __restrict__ Vo,
        float* __restrict__ out) {
    const int NT  = (MODE == 0 ? NQKV / 128 : DIM / 128);
    const int NWG = (MTOT / 128) * NT;
    int bid = blockIdx.x;
    bid = (bid & 7) * (NWG / 8) + (bid >> 3);         // XCD swizzle (NWG%8==0)
    int nt = bid % NT, mt = bid / NT;
    int m0 = mt * 128, n0 = nt * 128;
    __shared__ bf16s As[128][72];
    __shared__ bf16s Bs[128][72];
    int t = threadIdx.x;
    int lane = t & 63, w = t >> 6;
    int wr = w >> 1, wc = w & 1;
    int lr = lane & 15, lg = lane >> 4;
    f32x4 acc[4][4] = {};
    const int KI = (MODE == 0 ? DIM / 64 : 3 * DIM / 64);
    for (int it = 0; it < KI; ++it) {
        int seg = it / (DIM / 64);
        int k0  = (it % (DIM / 64)) * 64;
        const bf16s* Ap = A0;
        const bf16s* Bp = B0;
        if (MODE == 1) {
            Ap = (seg == 2) ? A1 : A0;
            Bp = (seg == 1) ? B1 : B0;
        }
        #pragma unroll
        for (int i = 0; i < 4; ++i) {
            int flat = i * 2048 + t * 8;
            int r = flat >> 6, c = flat & 63;
            *(uint4*)&As[r][c] = *(const uint4*)&Ap[(size_t)(m0 + r) * DIM + k0 + c];
            *(uint4*)&Bs[r][c] = *(const uint4*)&Bp[(size_t)(n0 + r) * DIM + k0 + c];
        }
        __syncthreads();
        #pragma unroll
        for (int kk = 0; kk < 2; ++kk) {
            bf16x8 af[4], bfr[4];
            #pragma unroll
            for (int i = 0; i < 4; ++i) {
                af[i]  = *(const bf16x8*)&As[wr*64 + i*16 + lr][kk*32 + lg*8];
                bfr[i] = *(const bf16x8*)&Bs[wc*64 + i*16 + lr][kk*32 + lg*8];
            }
            #pragma unroll
            for (int mi = 0; mi < 4; ++mi)
                #pragma unroll
                for (int ni = 0; ni < 4; ++ni)
                    acc[mi][ni] = __builtin_amdgcn_mfma_f32_16x16x32_bf16(
                        af[mi], bfr[ni], acc[mi][ni], 0, 0, 0);
        }
        __syncthreads();
    }
    if (MODE == 0) {
        #pragma unroll
        for (int mi = 0; mi < 4; ++mi) {
            int m_base = m0 + wr*64 + mi*16 + lg*4;
            int b = m_base >> 11, p = m_base & 2047;
            #pragma unroll
            for (int ni = 0; ni < 4; ++ni) {
                int n = n0 + wc*64 + ni*16 + lr;
                int which = n / DIM, within = n % DIM;
                int hh = within >> 6, d = within & 63;
                if (which == 2) {
                    float bb = bias[within];
                    uint2 pk;
                    pk.x = cvt_pk_bf16(acc[mi][ni][0] + bb, acc[mi][ni][1] + bb);
                    pk.y = cvt_pk_bf16(acc[mi][ni][2] + bb, acc[mi][ni][3] + bb);
                    *(uint2*)&Vo[(((size_t)(b*HEADS + hh))*HD + d)*PP + p] = pk;
                } else {
                    bf16s* dst = (which == 1) ? Ko : Qo;
                    #pragma unroll
                    for (int r = 0; r < 4; ++r)
                        dst[(((size_t)(b*HEADS + hh))*PP + p + r)*HD + d] =
                            f2bf(acc[mi][ni][r]);
                }
            }
        }
    } else {
        #pragma unroll
        for (int mi = 0; mi < 4; ++mi)
            #pragma unroll
            for (int ni = 0; ni < 4; ++ni)
                #pragma unroll
                for (int r = 0; r < 4; ++r) {
                    int m = m0 + wr*64 + mi*16 + lg*4 + r;
                    int n = n0 + wc*64 + ni*16 + lr;
                    out[(size_t)m * DIM + n] = acc[mi][ni][r] + bias[n];
                }
    }
}

// ------------------------------------------------------------ attention
// one block = one (b,h,qtile-of-128); 4 waves x 32 q-rows (2 subtiles of 16)
// swapped QK^T (lane owns one q per subtile); Q pre-scaled by 0.125*log2e;
// double-buffered K/V (register prefetch); defer-max;
// P round-trip via per-wave LDS (ushort4 write -> __syncthreads -> b128 read,
// the R3-proven pattern).
__global__ __launch_bounds__(256) void attn_kernel(
        const bf16s* __restrict__ Q, const bf16s* __restrict__ K,
        const bf16s* __restrict__ Vt,
        bf16s* __restrict__ Oh, bf16s* __restrict__ Ol) {
    const int NWG = BB * HEADS * (PP / QBLK);        // 768
    int orig = blockIdx.x;
    int wg = (orig & 7) * (NWG / 8) + (orig >> 3);   // XCD swizzle
    int qt  = wg & 15;
    int tmp = wg >> 4;
    int h   = tmp % HEADS;
    int b   = tmp / HEADS;
    const size_t headoff = ((size_t)(b * HEADS + h)) * PP * HD;
    const bf16s* Qh = Q  + headoff;
    const bf16s* Kh = K  + headoff;
    const bf16s* Vh = Vt + headoff;                  // [d][p]
    __shared__ bf16s Ks[2][64][72];
    __shared__ bf16s Vs[2][64][72];                  // rows = d, cols = kv
    __shared__ bf16s Ps[4][16][72];                  // per-wave P [q_local][kv]
    int t = threadIdx.x, lane = t & 63, w = t >> 6;
    int lr = lane & 15, lg = lane >> 4;
    int q0  = qt * QBLK;
    int qw0 = q0 + w * 32;                           // wave's 32 q rows
    bf16x8 qf[2][2];
    #pragma unroll
    for (int u = 0; u < 2; ++u) {
        qf[u][0] = *(const bf16x8*)&Qh[(size_t)(qw0 + 16*u + lr) * HD + lg*8];
        qf[u][1] = *(const bf16x8*)&Qh[(size_t)(qw0 + 16*u + lr) * HD + 32 + lg*8];
    }
    float m_run[2] = {-1e30f, -1e30f};
    float l_run[2] = {0.f, 0.f};
    f32x4 o[2][4] = {};
    // staging geometry (fixed per thread)
    int sr[2], sc[2];
    uint4 kreg[2], vreg[2];
    #pragma unroll
    for (int i = 0; i < 2; ++i) {
        int flat = i * 2048 + t * 8;
        sr[i] = flat >> 6; sc[i] = flat & 63;
        kreg[i] = *(const uint4*)&Kh[(size_t)sr[i] * HD + sc[i]];
        vreg[i] = *(const uint4*)&Vh[(size_t)sr[i] * PP + sc[i]];
    }
    #pragma unroll
    for (int i = 0; i < 2; ++i) {
        *(uint4*)&Ks[0][sr[i]][sc[i]] = kreg[i];
        *(uint4*)&Vs[0][sr[i]][sc[i]] = vreg[i];
    }
    __syncthreads();
    for (int j = 0; j < 32; ++j) {
        int cur = j & 1;
        if (j < 31) {                                // prefetch next tile -> regs
            #pragma unroll
            for (int i = 0; i < 2; ++i) {
                kreg[i] = *(const uint4*)&Kh[(size_t)((j+1)*64 + sr[i]) * HD + sc[i]];
                vreg[i] = *(const uint4*)&Vh[(size_t)sr[i] * PP + (j+1)*64 + sc[i]];
            }
        }
        // ---- QK^T (scores pre-scaled via Wq; exp2 domain)
        f32x4 s[2][4] = {};
        #pragma unroll
        for (int kk = 0; kk < 2; ++kk) {
            bf16x8 kf[4];
            #pragma unroll
            for (int n = 0; n < 4; ++n)
                kf[n] = *(const bf16x8*)&Ks[cur][n*16 + lr][kk*32 + lg*8];
            #pragma unroll
            for (int u = 0; u < 2; ++u)
                #pragma unroll
                for (int n = 0; n < 4; ++n)
                    s[u][n] = __builtin_amdgcn_mfma_f32_16x16x32_bf16(
                        kf[n], qf[u][kk], s[u][n], 0, 0, 0);
        }
        // ---- diagonal mask (rare, wave-uniform trigger)
        #pragma unroll
        for (int u = 0; u < 2; ++u) {
            if (((qw0 + 16*u) >> 6) == j) {
                int off = qw0 + 16*u + lr - j*64;    // in [0,64)
                if (((off >> 2) & 3) == lg) s[u][off >> 4][off & 3] = -1e30f;
            }
        }
        // ---- softmax + LDS P round-trip + PV per subtile
        #pragma unroll
        for (int u = 0; u < 2; ++u) {
            float mt = -1e30f;
            #pragma unroll
            for (int n = 0; n < 4; ++n)
                #pragma unroll
                for (int r = 0; r < 4; ++r) mt = fmaxf(mt, s[u][n][r]);
            mt = fmaxf(mt, __shfl_xor(mt, 16));
            mt = fmaxf(mt, __shfl_xor(mt, 32));
            if (!__all(mt <= m_run[u] + 8.f)) {      // defer-max rescale
                float mn = fmaxf(m_run[u], mt);
                float corr = exp2g(m_run[u] - mn);
                m_run[u] = mn;
                l_run[u] *= corr;
                #pragma unroll
                for (int r = 0; r < 4; ++r) {
                    float cq = __shfl(corr, lg*4 + r);
                    #pragma unroll
                    for (int nd = 0; nd < 4; ++nd) o[u][nd][r] *= cq;
                }
            }
            float rs = 0.f;
            #pragma unroll
            for (int n = 0; n < 4; ++n)
                #pragma unroll
                for (int r = 0; r < 4; ++r) {
                    float p = exp2g(s[u][n][r] - m_run[u]);
                    s[u][n][r] = p;
                    rs += p;
                }
            rs += __shfl_xor(rs, 16);
            rs += __shfl_xor(rs, 32);
            l_run[u] += rs;
            // P -> per-wave LDS: lane holds P[q=lr][kv=n*16+lg*4+r]
            #pragma unroll
            for (int n = 0; n < 4; ++n) {
                ushort4 pk;
                pk.x = (bf16s)(cvt_pk_bf16(s[u][n][0], s[u][n][1]) & 0xffffu);
                pk.y = (bf16s)(cvt_pk_bf16(s[u][n][0], s[u][n][1]) >> 16);
                pk.z = (bf16s)(cvt_pk_bf16(s[u][n][2], s[u][n][3]) & 0xffffu);
                pk.w = (bf16s)(cvt_pk_bf16(s[u][n][2], s[u][n][3]) >> 16);
                *(ushort4*)&Ps[w][lr][n*16 + lg*4] = pk;
            }
            __syncthreads();                         // order write->read (per-wave data)
            #pragma unroll
            for (int kk = 0; kk < 2; ++kk) {
                bf16x8 pf = *(const bf16x8*)&Ps[w][lr][kk*32 + lg*8];
                #pragma unroll
                for (int nd = 0; nd < 4; ++nd) {
                    bf16x8 vf = *(const bf16x8*)&Vs[cur][nd*16 + lr][kk*32 + lg*8];
                    o[u][nd] = __builtin_amdgcn_mfma_f32_16x16x32_bf16(
                        pf, vf, o[u][nd], 0, 0, 0);
                }
            }
        }
        if (j < 31) {                                // publish next tile
            __syncthreads();                         // all P-reads done; safe to overwrite dbuf
            #pragma unroll
            for (int i = 0; i < 2; ++i) {
                *(uint4*)&Ks[cur ^ 1][sr[i]][sc[i]] = kreg[i];
                *(uint4*)&Vs[cur ^ 1][sr[i]][sc[i]] = vreg[i];
            }
            __syncthreads();
        }
    }
    float invl[2][4];
    #pragma unroll
    for (int u = 0; u < 2; ++u)
        #pragma unroll
        for (int r = 0; r < 4; ++r)
            invl[u][r] = 1.0f / __shfl(l_run[u], lg*4 + r);
    #pragma unroll
    for (int u = 0; u < 2; ++u)
        #pragma unroll
        for (int nd = 0; nd < 4; ++nd)
            #pragma unroll
            for (int r = 0; r < 4; ++r) {
                int q = qw0 + 16*u + lg*4 + r;
                int d = nd*16 + lr;
                float v = o[u][nd][r] * invl[u][r];
                size_t idx = ((size_t)b * PP + q) * DIM + h * HD + d;
                bf16s hi = f2bf(v);
                Oh[idx] = hi;
                Ol[idx] = f2bf(v - bf2f(hi));
            }
}

// ---------------------------------------------------------------- launch
extern "C" void kernel_launch(void* const* d_in, const int* in_sizes, int n_in,
                              void* d_out, int out_size, void* d_ws, size_t ws_size,
                              hipStream_t stream) {
    const float* x    = (const float*)d_in[0];
    const float* ln_w = (const float*)d_in[1];
    const float* ln_b = (const float*)d_in[2];
    const float* Wq   = (const float*)d_in[3];
    const float* Wk   = (const float*)d_in[4];
    const float* Wv   = (const float*)d_in[5];
    const float* bv   = (const float*)d_in[6];
    const float* Wfc  = (const float*)d_in[7];
    const float* bfc  = (const float*)d_in[8];
    float* out = (float*)d_out;

    char* ws = (char*)d_ws;
    size_t off = 0;
    auto alloc = [&](size_t bytes) {
        void* p = ws + off;
        off += (bytes + 255) & ~(size_t)255;
        return p;
    };
    bf16s* xn     = (bf16s*)alloc((size_t)MTOT * DIM * 2);
    bf16s* Wqkv_t = (bf16s*)alloc((size_t)NQKV * DIM * 2);
    bf16s* Wfc_h  = (bf16s*)alloc((size_t)DIM * DIM * 2);
    bf16s* Wfc_l  = (bf16s*)alloc((size_t)DIM * DIM * 2);
    bf16s* Qb     = (bf16s*)alloc((size_t)MTOT * DIM * 2);
    bf16s* Kb     = (bf16s*)alloc((size_t)MTOT * DIM * 2);
    bf16s* Vtg    = (bf16s*)alloc((size_t)MTOT * DIM * 2);   // V^T [b,h,d,p]
    bf16s* Ah     = (bf16s*)alloc((size_t)MTOT * DIM * 2);
    bf16s* Al     = (bf16s*)alloc((size_t)MTOT * DIM * 2);

    const float SC = 0.125f * 1.44269504f;   // softmax scale * log2(e), folded into Wq

    ln_kernel<<<MTOT, 256, 0, stream>>>(x, ln_w, ln_b, xn);

    dim3 tb(32, 8);
    transpose_cast<false><<<dim3(24, 24), tb, 0, stream>>>(Wq, Wqkv_t,                 nullptr, DIM, DIM, SC);
    transpose_cast<false><<<dim3(24, 24), tb, 0, stream>>>(Wk, Wqkv_t + 768 * 768,     nullptr, DIM, DIM, 1.0f);
    transpose_cast<false><<<dim3(24, 24), tb, 0, stream>>>(Wv, Wqkv_t + 2 * 768 * 768, nullptr, DIM, DIM, 1.0f);
    transpose_cast<true ><<<dim3(24, 24), tb, 0, stream>>>(Wfc, Wfc_h, Wfc_l, DIM, DIM, 1.0f);

    gemm_bt<0><<<(MTOT / 128) * (NQKV / 128), 256, 0, stream>>>(
        xn, nullptr, Wqkv_t, nullptr, bv, Qb, Kb, Vtg, nullptr);

    attn_kernel<<<BB * HEADS * (PP / QBLK), 256, 0, stream>>>(Qb, Kb, Vtg, Ah, Al);

    gemm_bt<1><<<(MTOT / 128) * (DIM / 128), 256, 0, stream>>>(
        Ah, Al, Wfc_h, Wfc_l, bfc, nullptr, nullptr, nullptr, out);
}

// Round 8
// 255.082 us; speedup vs baseline: 1.6914x; 1.6914x over previous
//
#include <hip/hip_runtime.h>

#define DIM    768
#define HEADS  12
#define HD     64
#define BB     4
#define PP     2048
#define MTOT   8192   /* BB*PP */
#define NQKV   2304
#define QBLK   128

typedef unsigned short bf16s;                                   // bf16 storage
typedef short bf16x8 __attribute__((ext_vector_type(8)));       // MFMA A/B frag
typedef float f32x4  __attribute__((ext_vector_type(4)));       // MFMA C/D frag

__device__ __forceinline__ bf16s f2bf(float f) {
    unsigned int u = __float_as_uint(f);
    unsigned int r = u + 0x7fffu + ((u >> 16) & 1u);            // RNE
    return (bf16s)(r >> 16);
}
__device__ __forceinline__ float bf2f(bf16s s) {
    return __uint_as_float(((unsigned int)s) << 16);
}
__device__ __forceinline__ float exp2g(float x) {
    return __builtin_amdgcn_exp2f(x);                           // v_exp_f32
}
__device__ __forceinline__ unsigned cvt_pk_bf16(float a, float b) {
    unsigned r;
    asm("v_cvt_pk_bf16_f32 %0, %1, %2" : "=v"(r) : "v"(a), "v"(b));
    return r;                                                   // lo=bf16(a), hi=bf16(b)
}

// ---------------------------------------------------------------- LayerNorm
__global__ __launch_bounds__(256) void ln_kernel(
        const float* __restrict__ x, const float* __restrict__ w,
        const float* __restrict__ b, bf16s* __restrict__ xn) {
    int row = blockIdx.x;
    const float* xr = x + (size_t)row * DIM;
    int t = threadIdx.x;
    float v0 = xr[t], v1 = xr[t + 256], v2 = xr[t + 512];
    float s  = v0 + v1 + v2;
    float ss = v0*v0 + v1*v1 + v2*v2;
    for (int off = 32; off; off >>= 1) {
        s  += __shfl_down(s, off);
        ss += __shfl_down(ss, off);
    }
    __shared__ float red[8];
    int wid = t >> 6, lane = t & 63;
    if (lane == 0) { red[wid] = s; red[4 + wid] = ss; }
    __syncthreads();
    if (t == 0) {
        float S  = red[0] + red[1] + red[2] + red[3];
        float SS = red[4] + red[5] + red[6] + red[7];
        float mean = S * (1.0f / DIM);
        float var  = SS * (1.0f / DIM) - mean * mean;
        red[0] = mean;
        red[1] = rsqrtf(var + 1e-5f);
    }
    __syncthreads();
    float mean = red[0], inv = red[1];
    bf16s* xo = xn + (size_t)row * DIM;
    xo[t]       = f2bf((v0 - mean) * inv * w[t]       + b[t]);
    xo[t + 256] = f2bf((v1 - mean) * inv * w[t + 256] + b[t + 256]);
    xo[t + 512] = f2bf((v2 - mean) * inv * w[t + 512] + b[t + 512]);
}

// ------------------------------------------------- transpose + cast weights
// dst[n][k] = src[k][n] * scale
template<bool LO>
__global__ __launch_bounds__(256) void transpose_cast(
        const float* __restrict__ src, bf16s* __restrict__ dst,
        bf16s* __restrict__ dst_lo, int Kdim, int Ndim, float scale) {
    __shared__ float tile[32][33];
    int n0 = blockIdx.x * 32, k0 = blockIdx.y * 32;
    int tx = threadIdx.x, ty = threadIdx.y;
    #pragma unroll
    for (int i = 0; i < 4; ++i)
        tile[ty + 8*i][tx] = src[(size_t)(k0 + ty + 8*i) * Ndim + n0 + tx];
    __syncthreads();
    #pragma unroll
    for (int i = 0; i < 4; ++i) {
        float v = tile[tx][ty + 8*i] * scale;
        size_t oidx = (size_t)(n0 + ty + 8*i) * Kdim + k0 + tx;
        bf16s hi = f2bf(v);
        dst[oidx] = hi;
        if (LO) dst_lo[oidx] = f2bf(v - bf2f(hi));
    }
}

// ----------------------------------------------------------------- GEMM
// C[M x N] = A[M x 768(K)] @ Bt[N x 768]^T ; 128x128 tile, 4 waves (2x2 of 64x64)
// MODE 0: N=2304 -> Q(prescaled) [b,h,p,d], K [b,h,p,d], V^T [b,h,d,p] (+bv)
// MODE 1: N=768, K'=3*768 (Ah*Bh + Ah*Bl + Al*Bh), out fp32 + bfc
template<int MODE>
__global__ __launch_bounds__(256) void gemm_bt(
        const bf16s* __restrict__ A0, const bf16s* __restrict__ A1,
        const bf16s* __restrict__ B0, const bf16s* __restrict__ B1,
        const float* __restrict__ bias,
        bf16s* __restrict__ Qo, bf16s* __restrict__ Ko, bf16s* __restrict__ Vo,
        float* __restrict__ out) {
    const int NT  = (MODE == 0 ? NQKV / 128 : DIM / 128);
    const int NWG = (MTOT / 128) * NT;
    int bid = blockIdx.x;
    bid = (bid & 7) * (NWG / 8) + (bid >> 3);         // XCD swizzle (NWG%8==0)
    int nt = bid % NT, mt = bid / NT;
    int m0 = mt * 128, n0 = nt * 128;
    __shared__ bf16s As[128][72];
    __shared__ bf16s Bs[128][72];
    int t = threadIdx.x;
    int lane = t & 63, w = t >> 6;
    int wr = w >> 1, wc = w & 1;
    int lr = lane & 15, lg = lane >> 4;
    f32x4 acc[4][4] = {};
    const int KI = (MODE == 0 ? DIM / 64 : 3 * DIM / 64);
    for (int it = 0; it < KI; ++it) {
        int seg = it / (DIM / 64);
        int k0  = (it % (DIM / 64)) * 64;
        const bf16s* Ap = A0;
        const bf16s* Bp = B0;
        if (MODE == 1) {
            Ap = (seg == 2) ? A1 : A0;
            Bp = (seg == 1) ? B1 : B0;
        }
        #pragma unroll
        for (int i = 0; i < 4; ++i) {
            int flat = i * 2048 + t * 8;
            int r = flat >> 6, c = flat & 63;
            *(uint4*)&As[r][c] = *(const uint4*)&Ap[(size_t)(m0 + r) * DIM + k0 + c];
            *(uint4*)&Bs[r][c] = *(const uint4*)&Bp[(size_t)(n0 + r) * DIM + k0 + c];
        }
        __syncthreads();
        #pragma unroll
        for (int kk = 0; kk < 2; ++kk) {
            bf16x8 af[4], bfr[4];
            #pragma unroll
            for (int i = 0; i < 4; ++i) {
                af[i]  = *(const bf16x8*)&As[wr*64 + i*16 + lr][kk*32 + lg*8];
                bfr[i] = *(const bf16x8*)&Bs[wc*64 + i*16 + lr][kk*32 + lg*8];
            }
            #pragma unroll
            for (int mi = 0; mi < 4; ++mi)
                #pragma unroll
                for (int ni = 0; ni < 4; ++ni)
                    acc[mi][ni] = __builtin_amdgcn_mfma_f32_16x16x32_bf16(
                        af[mi], bfr[ni], acc[mi][ni], 0, 0, 0);
        }
        __syncthreads();
    }
    if (MODE == 0) {
        #pragma unroll
        for (int mi = 0; mi < 4; ++mi) {
            int m_base = m0 + wr*64 + mi*16 + lg*4;
            int b = m_base >> 11, p = m_base & 2047;
            #pragma unroll
            for (int ni = 0; ni < 4; ++ni) {
                int n = n0 + wc*64 + ni*16 + lr;
                int which = n / DIM, within = n % DIM;
                int hh = within >> 6, d = within & 63;
                if (which == 2) {
                    float bb = bias[within];
                    uint2 pk;
                    pk.x = cvt_pk_bf16(acc[mi][ni][0] + bb, acc[mi][ni][1] + bb);
                    pk.y = cvt_pk_bf16(acc[mi][ni][2] + bb, acc[mi][ni][3] + bb);
                    *(uint2*)&Vo[(((size_t)(b*HEADS + hh))*HD + d)*PP + p] = pk;
                } else {
                    bf16s* dst = (which == 1) ? Ko : Qo;
                    #pragma unroll
                    for (int r = 0; r < 4; ++r)
                        dst[(((size_t)(b*HEADS + hh))*PP + p + r)*HD + d] =
                            f2bf(acc[mi][ni][r]);
                }
            }
        }
    } else {
        #pragma unroll
        for (int mi = 0; mi < 4; ++mi)
            #pragma unroll
            for (int ni = 0; ni < 4; ++ni)
                #pragma unroll
                for (int r = 0; r < 4; ++r) {
                    int m = m0 + wr*64 + mi*16 + lg*4 + r;
                    int n = n0 + wc*64 + ni*16 + lr;
                    out[(size_t)m * DIM + n] = acc[mi][ni][r] + bias[n];
                }
    }
}

// ------------------------------------------------------------ attention
// one block = one (b,h,qtile-of-128); 4 waves x 32 q-rows (2 subtiles of 16)
// swapped QK^T (lane owns one q per subtile); Q pre-scaled by 0.125*log2e;
// double-buffered K/V (register prefetch); defer-max;
// diagonal mask via STATIC-indexed cndmask (no runtime ext_vector indexing);
// P round-trip: uint2 LDS write -> __syncthreads (fence) -> b128 read.
__global__ __launch_bounds__(256) void attn_kernel(
        const bf16s* __restrict__ Q, const bf16s* __restrict__ K,
        const bf16s* __restrict__ Vt,
        bf16s* __restrict__ Oh, bf16s* __restrict__ Ol) {
    const int NWG = BB * HEADS * (PP / QBLK);        // 768
    int orig = blockIdx.x;
    int wg = (orig & 7) * (NWG / 8) + (orig >> 3);   // XCD swizzle
    int qt  = wg & 15;
    int tmp = wg >> 4;
    int h   = tmp % HEADS;
    int b   = tmp / HEADS;
    const size_t headoff = ((size_t)(b * HEADS + h)) * PP * HD;
    const bf16s* Qh = Q  + headoff;
    const bf16s* Kh = K  + headoff;
    const bf16s* Vh = Vt + headoff;                  // [d][p]
    __shared__ bf16s Ks[2][64][72];
    __shared__ bf16s Vs[2][64][72];                  // rows = d, cols = kv
    __shared__ bf16s Ps[4][16][72];                  // per-wave P [q_local][kv]
    int t = threadIdx.x, lane = t & 63, w = t >> 6;
    int lr = lane & 15, lg = lane >> 4;
    int q0  = qt * QBLK;
    int qw0 = q0 + w * 32;                           // wave's 32 q rows
    bf16x8 qf[2][2];
    #pragma unroll
    for (int u = 0; u < 2; ++u) {
        qf[u][0] = *(const bf16x8*)&Qh[(size_t)(qw0 + 16*u + lr) * HD + lg*8];
        qf[u][1] = *(const bf16x8*)&Qh[(size_t)(qw0 + 16*u + lr) * HD + 32 + lg*8];
    }
    float m_run[2] = {-1e30f, -1e30f};
    float l_run[2] = {0.f, 0.f};
    f32x4 o[2][4] = {};
    // staging geometry (fixed per thread)
    int sr[2], sc[2];
    uint4 kreg[2], vreg[2];
    #pragma unroll
    for (int i = 0; i < 2; ++i) {
        int flat = i * 2048 + t * 8;
        sr[i] = flat >> 6; sc[i] = flat & 63;
        kreg[i] = *(const uint4*)&Kh[(size_t)sr[i] * HD + sc[i]];
        vreg[i] = *(const uint4*)&Vh[(size_t)sr[i] * PP + sc[i]];
    }
    #pragma unroll
    for (int i = 0; i < 2; ++i) {
        *(uint4*)&Ks[0][sr[i]][sc[i]] = kreg[i];
        *(uint4*)&Vs[0][sr[i]][sc[i]] = vreg[i];
    }
    __syncthreads();
    for (int j = 0; j < 32; ++j) {
        int cur = j & 1;
        if (j < 31) {                                // prefetch next tile -> regs
            #pragma unroll
            for (int i = 0; i < 2; ++i) {
                kreg[i] = *(const uint4*)&Kh[(size_t)((j+1)*64 + sr[i]) * HD + sc[i]];
                vreg[i] = *(const uint4*)&Vh[(size_t)sr[i] * PP + (j+1)*64 + sc[i]];
            }
        }
        // ---- QK^T (scores pre-scaled via Wq; exp2 domain)
        f32x4 s[2][4] = {};
        #pragma unroll
        for (int kk = 0; kk < 2; ++kk) {
            bf16x8 kf[4];
            #pragma unroll
            for (int n = 0; n < 4; ++n)
                kf[n] = *(const bf16x8*)&Ks[cur][n*16 + lr][kk*32 + lg*8];
            #pragma unroll
            for (int u = 0; u < 2; ++u)
                #pragma unroll
                for (int n = 0; n < 4; ++n)
                    s[u][n] = __builtin_amdgcn_mfma_f32_16x16x32_bf16(
                        kf[n], qf[u][kk], s[u][n], 0, 0, 0);
        }
        // ---- diagonal mask: wave-uniform guard + STATIC indices (stays in regs)
        #pragma unroll
        for (int u = 0; u < 2; ++u) {
            if (((qw0 + 16*u) >> 6) == j) {
                int qrel = qw0 + 16*u + lr - j*64;   // lane's q within this kv tile
                #pragma unroll
                for (int n = 0; n < 4; ++n)
                    #pragma unroll
                    for (int r = 0; r < 4; ++r)
                        if (n*16 + lg*4 + r == qrel) s[u][n][r] = -1e30f;
            }
        }
        // ---- softmax + LDS P round-trip + PV per subtile
        #pragma unroll
        for (int u = 0; u < 2; ++u) {
            float mt = -1e30f;
            #pragma unroll
            for (int n = 0; n < 4; ++n)
                #pragma unroll
                for (int r = 0; r < 4; ++r) mt = fmaxf(mt, s[u][n][r]);
            mt = fmaxf(mt, __shfl_xor(mt, 16));
            mt = fmaxf(mt, __shfl_xor(mt, 32));
            if (!__all(mt <= m_run[u] + 8.f)) {      // defer-max rescale
                float mn = fmaxf(m_run[u], mt);
                float corr = exp2g(m_run[u] - mn);
                m_run[u] = mn;
                l_run[u] *= corr;
                #pragma unroll
                for (int r = 0; r < 4; ++r) {
                    float cq = __shfl(corr, lg*4 + r);
                    #pragma unroll
                    for (int nd = 0; nd < 4; ++nd) o[u][nd][r] *= cq;
                }
            }
            float rs = 0.f;
            #pragma unroll
            for (int n = 0; n < 4; ++n)
                #pragma unroll
                for (int r = 0; r < 4; ++r) {
                    float p = exp2g(s[u][n][r] - m_run[u]);
                    s[u][n][r] = p;
                    rs += p;
                }
            rs += __shfl_xor(rs, 16);
            rs += __shfl_xor(rs, 32);
            l_run[u] += rs;
            // P -> per-wave LDS: lane holds P[q=lr][kv=n*16+lg*4+r]
            #pragma unroll
            for (int n = 0; n < 4; ++n) {
                uint2 pk;
                pk.x = cvt_pk_bf16(s[u][n][0], s[u][n][1]);
                pk.y = cvt_pk_bf16(s[u][n][2], s[u][n][3]);
                *(uint2*)&Ps[w][lr][n*16 + lg*4] = pk;
            }
            __syncthreads();                         // fence: order P write->read
            #pragma unroll
            for (int kk = 0; kk < 2; ++kk) {
                bf16x8 pf = *(const bf16x8*)&Ps[w][lr][kk*32 + lg*8];
                #pragma unroll
                for (int nd = 0; nd < 4; ++nd) {
                    bf16x8 vf = *(const bf16x8*)&Vs[cur][nd*16 + lr][kk*32 + lg*8];
                    o[u][nd] = __builtin_amdgcn_mfma_f32_16x16x32_bf16(
                        pf, vf, o[u][nd], 0, 0, 0);
                }
            }
        }
        if (j < 31) {                                // publish next tile
            // (the two P-barriers above already keep waves within one iter
            //  of each other, so writing cur^1 here cannot race a reader)
            #pragma unroll
            for (int i = 0; i < 2; ++i) {
                *(uint4*)&Ks[cur ^ 1][sr[i]][sc[i]] = kreg[i];
                *(uint4*)&Vs[cur ^ 1][sr[i]][sc[i]] = vreg[i];
            }
            __syncthreads();
        }
    }
    float invl[2][4];
    #pragma unroll
    for (int u = 0; u < 2; ++u)
        #pragma unroll
        for (int r = 0; r < 4; ++r)
            invl[u][r] = 1.0f / __shfl(l_run[u], lg*4 + r);
    #pragma unroll
    for (int u = 0; u < 2; ++u)
        #pragma unroll
        for (int nd = 0; nd < 4; ++nd)
            #pragma unroll
            for (int r = 0; r < 4; ++r) {
                int q = qw0 + 16*u + lg*4 + r;
                int d = nd*16 + lr;
                float v = o[u][nd][r] * invl[u][r];
                size_t idx = ((size_t)b * PP + q) * DIM + h * HD + d;
                bf16s hi = f2bf(v);
                Oh[idx] = hi;
                Ol[idx] = f2bf(v - bf2f(hi));
            }
}

// ---------------------------------------------------------------- launch
extern "C" void kernel_launch(void* const* d_in, const int* in_sizes, int n_in,
                              void* d_out, int out_size, void* d_ws, size_t ws_size,
                              hipStream_t stream) {
    const float* x    = (const float*)d_in[0];
    const float* ln_w = (const float*)d_in[1];
    const float* ln_b = (const float*)d_in[2];
    const float* Wq   = (const float*)d_in[3];
    const float* Wk   = (const float*)d_in[4];
    const float* Wv   = (const float*)d_in[5];
    const float* bv   = (const float*)d_in[6];
    const float* Wfc  = (const float*)d_in[7];
    const float* bfc  = (const float*)d_in[8];
    float* out = (float*)d_out;

    char* ws = (char*)d_ws;
    size_t off = 0;
    auto alloc = [&](size_t bytes) {
        void* p = ws + off;
        off += (bytes + 255) & ~(size_t)255;
        return p;
    };
    bf16s* xn     = (bf16s*)alloc((size_t)MTOT * DIM * 2);
    bf16s* Wqkv_t = (bf16s*)alloc((size_t)NQKV * DIM * 2);
    bf16s* Wfc_h  = (bf16s*)alloc((size_t)DIM * DIM * 2);
    bf16s* Wfc_l  = (bf16s*)alloc((size_t)DIM * DIM * 2);
    bf16s* Qb     = (bf16s*)alloc((size_t)MTOT * DIM * 2);
    bf16s* Kb     = (bf16s*)alloc((size_t)MTOT * DIM * 2);
    bf16s* Vtg    = (bf16s*)alloc((size_t)MTOT * DIM * 2);   // V^T [b,h,d,p]
    bf16s* Ah     = (bf16s*)alloc((size_t)MTOT * DIM * 2);
    bf16s* Al     = (bf16s*)alloc((size_t)MTOT * DIM * 2);

    const float SC = 0.125f * 1.44269504f;   // softmax scale * log2(e), folded into Wq

    ln_kernel<<<MTOT, 256, 0, stream>>>(x, ln_w, ln_b, xn);

    dim3 tb(32, 8);
    transpose_cast<false><<<dim3(24, 24), tb, 0, stream>>>(Wq, Wqkv_t,                 nullptr, DIM, DIM, SC);
    transpose_cast<false><<<dim3(24, 24), tb, 0, stream>>>(Wk, Wqkv_t + 768 * 768,     nullptr, DIM, DIM, 1.0f);
    transpose_cast<false><<<dim3(24, 24), tb, 0, stream>>>(Wv, Wqkv_t + 2 * 768 * 768, nullptr, DIM, DIM, 1.0f);
    transpose_cast<true ><<<dim3(24, 24), tb, 0, stream>>>(Wfc, Wfc_h, Wfc_l, DIM, DIM, 1.0f);

    gemm_bt<0><<<(MTOT / 128) * (NQKV / 128), 256, 0, stream>>>(
        xn, nullptr, Wqkv_t, nullptr, bv, Qb, Kb, Vtg, nullptr);

    attn_kernel<<<BB * HEADS * (PP / QBLK), 256, 0, stream>>>(Qb, Kb, Vtg, Ah, Al);

    gemm_bt<1><<<(MTOT / 128) * (DIM / 128), 256, 0, stream>>>(
        Ah, Al, Wfc_h, Wfc_l, bfc, nullptr, nullptr, nullptr, out);
}

// Round 9
// 205.937 us; speedup vs baseline: 2.0950x; 1.2386x over previous
//
#include <hip/hip_runtime.h>

#define DIM    768
#define HEADS  12
#define HD     64
#define BB     4
#define PP     2048
#define MTOT   8192   /* BB*PP */
#define NQKV   2304
#define QBLK   128

typedef unsigned short bf16s;                                   // bf16 storage
typedef short bf16x8 __attribute__((ext_vector_type(8)));       // MFMA A/B frag
typedef float f32x4  __attribute__((ext_vector_type(4)));       // MFMA C/D frag

__device__ __forceinline__ bf16s f2bf(float f) {
    unsigned int u = __float_as_uint(f);
    unsigned int r = u + 0x7fffu + ((u >> 16) & 1u);            // RNE
    return (bf16s)(r >> 16);
}
__device__ __forceinline__ float bf2f(bf16s s) {
    return __uint_as_float(((unsigned int)s) << 16);
}
__device__ __forceinline__ float exp2g(float x) {
    return __builtin_amdgcn_exp2f(x);                           // v_exp_f32
}
__device__ __forceinline__ unsigned cvt_pk_bf16(float a, float b) {
    unsigned r;
    asm("v_cvt_pk_bf16_f32 %0, %1, %2" : "=v"(r) : "v"(a), "v"(b));
    return r;                                                   // lo=bf16(a), hi=bf16(b)
}

// ---------------------------------------------------------------- LayerNorm
__global__ __launch_bounds__(256) void ln_kernel(
        const float* __restrict__ x, const float* __restrict__ w,
        const float* __restrict__ b, bf16s* __restrict__ xn) {
    int row = blockIdx.x;
    const float* xr = x + (size_t)row * DIM;
    int t = threadIdx.x;
    float v0 = xr[t], v1 = xr[t + 256], v2 = xr[t + 512];
    float s  = v0 + v1 + v2;
    float ss = v0*v0 + v1*v1 + v2*v2;
    for (int off = 32; off; off >>= 1) {
        s  += __shfl_down(s, off);
        ss += __shfl_down(ss, off);
    }
    __shared__ float red[8];
    int wid = t >> 6, lane = t & 63;
    if (lane == 0) { red[wid] = s; red[4 + wid] = ss; }
    __syncthreads();
    if (t == 0) {
        float S  = red[0] + red[1] + red[2] + red[3];
        float SS = red[4] + red[5] + red[6] + red[7];
        float mean = S * (1.0f / DIM);
        float var  = SS * (1.0f / DIM) - mean * mean;
        red[0] = mean;
        red[1] = rsqrtf(var + 1e-5f);
    }
    __syncthreads();
    float mean = red[0], inv = red[1];
    bf16s* xo = xn + (size_t)row * DIM;
    xo[t]       = f2bf((v0 - mean) * inv * w[t]       + b[t]);
    xo[t + 256] = f2bf((v1 - mean) * inv * w[t + 256] + b[t + 256]);
    xo[t + 512] = f2bf((v2 - mean) * inv * w[t + 512] + b[t + 512]);
}

// ------------------------------------------------- transpose + cast weights
// dst[n][k] = src[k][n] * scale
template<bool LO>
__global__ __launch_bounds__(256) void transpose_cast(
        const float* __restrict__ src, bf16s* __restrict__ dst,
        bf16s* __restrict__ dst_lo, int Kdim, int Ndim, float scale) {
    __shared__ float tile[32][33];
    int n0 = blockIdx.x * 32, k0 = blockIdx.y * 32;
    int tx = threadIdx.x, ty = threadIdx.y;
    #pragma unroll
    for (int i = 0; i < 4; ++i)
        tile[ty + 8*i][tx] = src[(size_t)(k0 + ty + 8*i) * Ndim + n0 + tx];
    __syncthreads();
    #pragma unroll
    for (int i = 0; i < 4; ++i) {
        float v = tile[tx][ty + 8*i] * scale;
        size_t oidx = (size_t)(n0 + ty + 8*i) * Kdim + k0 + tx;
        bf16s hi = f2bf(v);
        dst[oidx] = hi;
        if (LO) dst_lo[oidx] = f2bf(v - bf2f(hi));
    }
}

// ----------------------------------------------------------------- GEMM
// C[M x N] = A[M x 768(K)] @ Bt[N x 768]^T ; 128x128 tile, 4 waves (2x2 of 64x64)
// MODE 0: N=2304 -> Q(prescaled) [b,h,p,d], K [b,h,p,d], V^T [b,h,d,p] (+bv)
// MODE 1: N=768, K'=3*768 (Ah*Bh + Ah*Bl + Al*Bh), out fp32 + bfc
template<int MODE>
__global__ __launch_bounds__(256) void gemm_bt(
        const bf16s* __restrict__ A0, const bf16s* __restrict__ A1,
        const bf16s* __restrict__ B0, const bf16s* __restrict__ B1,
        const float* __restrict__ bias,
        bf16s* __restrict__ Qo, bf16s* __restrict__ Ko, bf16s* __restrict__ Vo,
        float* __restrict__ out) {
    const int NT  = (MODE == 0 ? NQKV / 128 : DIM / 128);
    const int NWG = (MTOT / 128) * NT;
    int bid = blockIdx.x;
    bid = (bid & 7) * (NWG / 8) + (bid >> 3);         // XCD swizzle (NWG%8==0)
    int nt = bid % NT, mt = bid / NT;
    int m0 = mt * 128, n0 = nt * 128;
    __shared__ bf16s As[128][72];
    __shared__ bf16s Bs[128][72];
    int t = threadIdx.x;
    int lane = t & 63, w = t >> 6;
    int wr = w >> 1, wc = w & 1;
    int lr = lane & 15, lg = lane >> 4;
    f32x4 acc[4][4] = {};
    const int KI = (MODE == 0 ? DIM / 64 : 3 * DIM / 64);
    for (int it = 0; it < KI; ++it) {
        int seg = it / (DIM / 64);
        int k0  = (it % (DIM / 64)) * 64;
        const bf16s* Ap = A0;
        const bf16s* Bp = B0;
        if (MODE == 1) {
            Ap = (seg == 2) ? A1 : A0;
            Bp = (seg == 1) ? B1 : B0;
        }
        #pragma unroll
        for (int i = 0; i < 4; ++i) {
            int flat = i * 2048 + t * 8;
            int r = flat >> 6, c = flat & 63;
            *(uint4*)&As[r][c] = *(const uint4*)&Ap[(size_t)(m0 + r) * DIM + k0 + c];
            *(uint4*)&Bs[r][c] = *(const uint4*)&Bp[(size_t)(n0 + r) * DIM + k0 + c];
        }
        __syncthreads();
        #pragma unroll
        for (int kk = 0; kk < 2; ++kk) {
            bf16x8 af[4], bfr[4];
            #pragma unroll
            for (int i = 0; i < 4; ++i) {
                af[i]  = *(const bf16x8*)&As[wr*64 + i*16 + lr][kk*32 + lg*8];
                bfr[i] = *(const bf16x8*)&Bs[wc*64 + i*16 + lr][kk*32 + lg*8];
            }
            #pragma unroll
            for (int mi = 0; mi < 4; ++mi)
                #pragma unroll
                for (int ni = 0; ni < 4; ++ni)
                    acc[mi][ni] = __builtin_amdgcn_mfma_f32_16x16x32_bf16(
                        af[mi], bfr[ni], acc[mi][ni], 0, 0, 0);
        }
        __syncthreads();
    }
    if (MODE == 0) {
        #pragma unroll
        for (int mi = 0; mi < 4; ++mi) {
            int m_base = m0 + wr*64 + mi*16 + lg*4;
            int b = m_base >> 11, p = m_base & 2047;
            #pragma unroll
            for (int ni = 0; ni < 4; ++ni) {
                int n = n0 + wc*64 + ni*16 + lr;
                int which = n / DIM, within = n % DIM;
                int hh = within >> 6, d = within & 63;
                if (which == 2) {
                    float bb = bias[within];
                    uint2 pk;
                    pk.x = cvt_pk_bf16(acc[mi][ni][0] + bb, acc[mi][ni][1] + bb);
                    pk.y = cvt_pk_bf16(acc[mi][ni][2] + bb, acc[mi][ni][3] + bb);
                    *(uint2*)&Vo[(((size_t)(b*HEADS + hh))*HD + d)*PP + p] = pk;
                } else {
                    bf16s* dst = (which == 1) ? Ko : Qo;
                    #pragma unroll
                    for (int r = 0; r < 4; ++r)
                        dst[(((size_t)(b*HEADS + hh))*PP + p + r)*HD + d] =
                            f2bf(acc[mi][ni][r]);
                }
            }
        }
    } else {
        #pragma unroll
        for (int mi = 0; mi < 4; ++mi)
            #pragma unroll
            for (int ni = 0; ni < 4; ++ni)
                #pragma unroll
                for (int r = 0; r < 4; ++r) {
                    int m = m0 + wr*64 + mi*16 + lg*4 + r;
                    int n = n0 + wc*64 + ni*16 + lr;
                    out[(size_t)m * DIM + n] = acc[mi][ni][r] + bias[n];
                }
    }
}

// ------------------------------------------------------------ attention
// one block = one (b,h,qtile-of-128); 4 waves x 32 q-rows (2 subtiles of 16)
// swapped QK^T (lane owns one q per subtile); Q pre-scaled by 0.125*log2e;
// double-buffered K/V (register prefetch); defer-max; static-index diag mask;
// V fragments hoisted to regs (reused across both subtiles);
// P round-trip per-wave LDS: write -> s_waitcnt lgkmcnt(0) + sched_barrier
// (same-wave DS is in-order; NO __syncthreads needed for per-wave data);
// ONE full barrier per iter (dbuf publish).
__global__ __launch_bounds__(256, 3) void attn_kernel(
        const bf16s* __restrict__ Q, const bf16s* __restrict__ K,
        const bf16s* __restrict__ Vt,
        bf16s* __restrict__ Oh, bf16s* __restrict__ Ol) {
    const int NWG = BB * HEADS * (PP / QBLK);        // 768
    int orig = blockIdx.x;
    int wg = (orig & 7) * (NWG / 8) + (orig >> 3);   // XCD swizzle
    int qt  = wg & 15;
    int tmp = wg >> 4;
    int h   = tmp % HEADS;
    int b   = tmp / HEADS;
    const size_t headoff = ((size_t)(b * HEADS + h)) * PP * HD;
    const bf16s* Qh = Q  + headoff;
    const bf16s* Kh = K  + headoff;
    const bf16s* Vh = Vt + headoff;                  // [d][p]
    __shared__ bf16s Ks[2][64][72];
    __shared__ bf16s Vs[2][64][72];                  // rows = d, cols = kv
    __shared__ bf16s Ps[4][16][72];                  // per-wave P [q_local][kv]
    int t = threadIdx.x, lane = t & 63, w = t >> 6;
    int lr = lane & 15, lg = lane >> 4;
    int q0  = qt * QBLK;
    int qw0 = q0 + w * 32;                           // wave's 32 q rows
    bf16x8 qf[2][2];
    #pragma unroll
    for (int u = 0; u < 2; ++u) {
        qf[u][0] = *(const bf16x8*)&Qh[(size_t)(qw0 + 16*u + lr) * HD + lg*8];
        qf[u][1] = *(const bf16x8*)&Qh[(size_t)(qw0 + 16*u + lr) * HD + 32 + lg*8];
    }
    float m_run[2] = {-1e30f, -1e30f};
    float l_run[2] = {0.f, 0.f};
    f32x4 o[2][4] = {};
    // staging geometry (fixed per thread)
    int sr[2], sc[2];
    uint4 kreg[2], vreg[2];
    #pragma unroll
    for (int i = 0; i < 2; ++i) {
        int flat = i * 2048 + t * 8;
        sr[i] = flat >> 6; sc[i] = flat & 63;
        kreg[i] = *(const uint4*)&Kh[(size_t)sr[i] * HD + sc[i]];
        vreg[i] = *(const uint4*)&Vh[(size_t)sr[i] * PP + sc[i]];
    }
    #pragma unroll
    for (int i = 0; i < 2; ++i) {
        *(uint4*)&Ks[0][sr[i]][sc[i]] = kreg[i];
        *(uint4*)&Vs[0][sr[i]][sc[i]] = vreg[i];
    }
    __syncthreads();
    for (int j = 0; j < 32; ++j) {
        int cur = j & 1;
        if (j < 31) {                                // prefetch next tile -> regs
            #pragma unroll
            for (int i = 0; i < 2; ++i) {
                kreg[i] = *(const uint4*)&Kh[(size_t)((j+1)*64 + sr[i]) * HD + sc[i]];
                vreg[i] = *(const uint4*)&Vh[(size_t)sr[i] * PP + (j+1)*64 + sc[i]];
            }
        }
        // ---- QK^T (scores pre-scaled via Wq; exp2 domain)
        f32x4 s[2][4] = {};
        #pragma unroll
        for (int kk = 0; kk < 2; ++kk) {
            bf16x8 kf[4];
            #pragma unroll
            for (int n = 0; n < 4; ++n)
                kf[n] = *(const bf16x8*)&Ks[cur][n*16 + lr][kk*32 + lg*8];
            #pragma unroll
            for (int u = 0; u < 2; ++u)
                #pragma unroll
                for (int n = 0; n < 4; ++n)
                    s[u][n] = __builtin_amdgcn_mfma_f32_16x16x32_bf16(
                        kf[n], qf[u][kk], s[u][n], 0, 0, 0);
        }
        // ---- diagonal mask: wave-uniform guard + STATIC indices (stays in regs)
        #pragma unroll
        for (int u = 0; u < 2; ++u) {
            if (((qw0 + 16*u) >> 6) == j) {
                int qrel = qw0 + 16*u + lr - j*64;   // lane's q within this kv tile
                #pragma unroll
                for (int n = 0; n < 4; ++n)
                    #pragma unroll
                    for (int r = 0; r < 4; ++r)
                        if (n*16 + lg*4 + r == qrel) s[u][n][r] = -1e30f;
            }
        }
        // ---- V fragments -> regs once per iter (shared by both subtiles)
        bf16x8 vfreg[2][4];
        #pragma unroll
        for (int kk = 0; kk < 2; ++kk)
            #pragma unroll
            for (int nd = 0; nd < 4; ++nd)
                vfreg[kk][nd] = *(const bf16x8*)&Vs[cur][nd*16 + lr][kk*32 + lg*8];
        // ---- softmax + per-wave LDS P round-trip + PV per subtile
        #pragma unroll
        for (int u = 0; u < 2; ++u) {
            float mt = -1e30f;
            #pragma unroll
            for (int n = 0; n < 4; ++n)
                #pragma unroll
                for (int r = 0; r < 4; ++r) mt = fmaxf(mt, s[u][n][r]);
            mt = fmaxf(mt, __shfl_xor(mt, 16));
            mt = fmaxf(mt, __shfl_xor(mt, 32));
            if (!__all(mt <= m_run[u] + 8.f)) {      // defer-max rescale
                float mn = fmaxf(m_run[u], mt);
                float corr = exp2g(m_run[u] - mn);
                m_run[u] = mn;
                l_run[u] *= corr;
                #pragma unroll
                for (int r = 0; r < 4; ++r) {
                    float cq = __shfl(corr, lg*4 + r);
                    #pragma unroll
                    for (int nd = 0; nd < 4; ++nd) o[u][nd][r] *= cq;
                }
            }
            float rs = 0.f;
            #pragma unroll
            for (int n = 0; n < 4; ++n)
                #pragma unroll
                for (int r = 0; r < 4; ++r) {
                    float p = exp2g(s[u][n][r] - m_run[u]);
                    s[u][n][r] = p;
                    rs += p;
                }
            rs += __shfl_xor(rs, 16);
            rs += __shfl_xor(rs, 32);
            l_run[u] += rs;
            // P -> per-wave LDS: lane holds P[q=lr][kv=n*16+lg*4+r]
            #pragma unroll
            for (int n = 0; n < 4; ++n) {
                uint2 pk;
                pk.x = cvt_pk_bf16(s[u][n][0], s[u][n][1]);
                pk.y = cvt_pk_bf16(s[u][n][2], s[u][n][3]);
                *(uint2*)&Ps[w][lr][n*16 + lg*4] = pk;
            }
            // same-wave DS is in-order; force compiler ordering + drain
            asm volatile("s_waitcnt lgkmcnt(0)" ::: "memory");
            __builtin_amdgcn_sched_barrier(0);
            #pragma unroll
            for (int kk = 0; kk < 2; ++kk) {
                bf16x8 pf = *(const bf16x8*)&Ps[w][lr][kk*32 + lg*8];
                #pragma unroll
                for (int nd = 0; nd < 4; ++nd)
                    o[u][nd] = __builtin_amdgcn_mfma_f32_16x16x32_bf16(
                        pf, vfreg[kk][nd], o[u][nd], 0, 0, 0);
            }
        }
        if (j < 31) {                                // publish next tile
            #pragma unroll
            for (int i = 0; i < 2; ++i) {
                *(uint4*)&Ks[cur ^ 1][sr[i]][sc[i]] = kreg[i];
                *(uint4*)&Vs[cur ^ 1][sr[i]][sc[i]] = vreg[i];
            }
            __syncthreads();                         // one full barrier per iter
        }
    }
    float invl[2][4];
    #pragma unroll
    for (int u = 0; u < 2; ++u)
        #pragma unroll
        for (int r = 0; r < 4; ++r)
            invl[u][r] = 1.0f / __shfl(l_run[u], lg*4 + r);
    #pragma unroll
    for (int u = 0; u < 2; ++u)
        #pragma unroll
        for (int nd = 0; nd < 4; ++nd)
            #pragma unroll
            for (int r = 0; r < 4; ++r) {
                int q = qw0 + 16*u + lg*4 + r;
                int d = nd*16 + lr;
                float v = o[u][nd][r] * invl[u][r];
                size_t idx = ((size_t)b * PP + q) * DIM + h * HD + d;
                bf16s hi = f2bf(v);
                Oh[idx] = hi;
                Ol[idx] = f2bf(v - bf2f(hi));
            }
}

// ---------------------------------------------------------------- launch
extern "C" void kernel_launch(void* const* d_in, const int* in_sizes, int n_in,
                              void* d_out, int out_size, void* d_ws, size_t ws_size,
                              hipStream_t stream) {
    const float* x    = (const float*)d_in[0];
    const float* ln_w = (const float*)d_in[1];
    const float* ln_b = (const float*)d_in[2];
    const float* Wq   = (const float*)d_in[3];
    const float* Wk   = (const float*)d_in[4];
    const float* Wv   = (const float*)d_in[5];
    const float* bv   = (const float*)d_in[6];
    const float* Wfc  = (const float*)d_in[7];
    const float* bfc  = (const float*)d_in[8];
    float* out = (float*)d_out;

    char* ws = (char*)d_ws;
    size_t off = 0;
    auto alloc = [&](size_t bytes) {
        void* p = ws + off;
        off += (bytes + 255) & ~(size_t)255;
        return p;
    };
    bf16s* xn     = (bf16s*)alloc((size_t)MTOT * DIM * 2);
    bf16s* Wqkv_t = (bf16s*)alloc((size_t)NQKV * DIM * 2);
    bf16s* Wfc_h  = (bf16s*)alloc((size_t)DIM * DIM * 2);
    bf16s* Wfc_l  = (bf16s*)alloc((size_t)DIM * DIM * 2);
    bf16s* Qb     = (bf16s*)alloc((size_t)MTOT * DIM * 2);
    bf16s* Kb     = (bf16s*)alloc((size_t)MTOT * DIM * 2);
    bf16s* Vtg    = (bf16s*)alloc((size_t)MTOT * DIM * 2);   // V^T [b,h,d,p]
    bf16s* Ah     = (bf16s*)alloc((size_t)MTOT * DIM * 2);
    bf16s* Al     = (bf16s*)alloc((size_t)MTOT * DIM * 2);

    const float SC = 0.125f * 1.44269504f;   // softmax scale * log2(e), folded into Wq

    ln_kernel<<<MTOT, 256, 0, stream>>>(x, ln_w, ln_b, xn);

    dim3 tb(32, 8);
    transpose_cast<false><<<dim3(24, 24), tb, 0, stream>>>(Wq, Wqkv_t,                 nullptr, DIM, DIM, SC);
    transpose_cast<false><<<dim3(24, 24), tb, 0, stream>>>(Wk, Wqkv_t + 768 * 768,     nullptr, DIM, DIM, 1.0f);
    transpose_cast<false><<<dim3(24, 24), tb, 0, stream>>>(Wv, Wqkv_t + 2 * 768 * 768, nullptr, DIM, DIM, 1.0f);
    transpose_cast<true ><<<dim3(24, 24), tb, 0, stream>>>(Wfc, Wfc_h, Wfc_l, DIM, DIM, 1.0f);

    gemm_bt<0><<<(MTOT / 128) * (NQKV / 128), 256, 0, stream>>>(
        xn, nullptr, Wqkv_t, nullptr, bv, Qb, Kb, Vtg, nullptr);

    attn_kernel<<<BB * HEADS * (PP / QBLK), 256, 0, stream>>>(Qb, Kb, Vtg, Ah, Al);

    gemm_bt<1><<<(MTOT / 128) * (DIM / 128), 256, 0, stream>>>(
        Ah, Al, Wfc_h, Wfc_l, bfc, nullptr, nullptr, nullptr, out);
}

// Round 11
// 203.038 us; speedup vs baseline: 2.1250x; 1.0143x over previous
//
#include <hip/hip_runtime.h>

#define DIM    768
#define HEADS  12
#define HD     64
#define BB     4
#define PP     2048
#define MTOT   8192   /* BB*PP */
#define NQKV   2304
#define QBLK   128

typedef unsigned short bf16s;                                   // bf16 storage
typedef short bf16x8 __attribute__((ext_vector_type(8)));       // MFMA A/B frag
typedef float f32x4  __attribute__((ext_vector_type(4)));       // MFMA C/D frag

typedef const __attribute__((address_space(1))) unsigned int g_u32;
typedef __attribute__((address_space(3))) unsigned int lds_u32;

__device__ __forceinline__ bf16s f2bf(float f) {
    unsigned int u = __float_as_uint(f);
    unsigned int r = u + 0x7fffu + ((u >> 16) & 1u);            // RNE
    return (bf16s)(r >> 16);
}
__device__ __forceinline__ float bf2f(bf16s s) {
    return __uint_as_float(((unsigned int)s) << 16);
}
__device__ __forceinline__ float exp2g(float x) {
    return __builtin_amdgcn_exp2f(x);                           // v_exp_f32
}
__device__ __forceinline__ unsigned cvt_pk_bf16(float a, float b) {
    unsigned r;
    asm("v_cvt_pk_bf16_f32 %0, %1, %2" : "=v"(r) : "v"(a), "v"(b));
    return r;                                                   // lo=bf16(a), hi=bf16(b)
}

// ---------------------------------------------------------------- LayerNorm
__global__ __launch_bounds__(256) void ln_kernel(
        const float* __restrict__ x, const float* __restrict__ w,
        const float* __restrict__ b, bf16s* __restrict__ xn) {
    int row = blockIdx.x;
    const float* xr = x + (size_t)row * DIM;
    int t = threadIdx.x;
    float v0 = xr[t], v1 = xr[t + 256], v2 = xr[t + 512];
    float s  = v0 + v1 + v2;
    float ss = v0*v0 + v1*v1 + v2*v2;
    for (int off = 32; off; off >>= 1) {
        s  += __shfl_down(s, off);
        ss += __shfl_down(ss, off);
    }
    __shared__ float red[8];
    int wid = t >> 6, lane = t & 63;
    if (lane == 0) { red[wid] = s; red[4 + wid] = ss; }
    __syncthreads();
    if (t == 0) {
        float S  = red[0] + red[1] + red[2] + red[3];
        float SS = red[4] + red[5] + red[6] + red[7];
        float mean = S * (1.0f / DIM);
        float var  = SS * (1.0f / DIM) - mean * mean;
        red[0] = mean;
        red[1] = rsqrtf(var + 1e-5f);
    }
    __syncthreads();
    float mean = red[0], inv = red[1];
    bf16s* xo = xn + (size_t)row * DIM;
    xo[t]       = f2bf((v0 - mean) * inv * w[t]       + b[t]);
    xo[t + 256] = f2bf((v1 - mean) * inv * w[t + 256] + b[t + 256]);
    xo[t + 512] = f2bf((v2 - mean) * inv * w[t + 512] + b[t + 512]);
}

// ------------------------------------------------- transpose + cast weights
// dst[n][k] = src[k][n] * scale
template<bool LO>
__global__ __launch_bounds__(256) void transpose_cast(
        const float* __restrict__ src, bf16s* __restrict__ dst,
        bf16s* __restrict__ dst_lo, int Kdim, int Ndim, float scale) {
    __shared__ float tile[32][33];
    int n0 = blockIdx.x * 32, k0 = blockIdx.y * 32;
    int tx = threadIdx.x, ty = threadIdx.y;
    #pragma unroll
    for (int i = 0; i < 4; ++i)
        tile[ty + 8*i][tx] = src[(size_t)(k0 + ty + 8*i) * Ndim + n0 + tx];
    __syncthreads();
    #pragma unroll
    for (int i = 0; i < 4; ++i) {
        float v = tile[tx][ty + 8*i] * scale;
        size_t oidx = (size_t)(n0 + ty + 8*i) * Kdim + k0 + tx;
        bf16s hi = f2bf(v);
        dst[oidx] = hi;
        if (LO) dst_lo[oidx] = f2bf(v - bf2f(hi));
    }
}

// ----------------------------------------------------------------- GEMM
// C[M x N] = A[M x 768(K)] @ Bt[N x 768]^T ; 128x128 tile, 4 waves (2x2 of 64x64)
// Staging: global_load_lds width=16 into LINEAR [128][64] LDS with
// source-side chunk-XOR swizzle (rule #21): LDS[r][c] holds A[r][c ^ ((r&7)<<3)];
// reads apply the same XOR -> conflict-free ds_read_b128.
// 128x64 tile = 8192 elems = 256 thr x 8 elems x 4 issues.
// MODE 0: N=2304 -> Q(prescaled) [b,h,p,d], K [b,h,p,d], V^T [b,h,d,p] (+bv)
// MODE 1: N=768, K'=3*768 (Ah*Bh + Ah*Bl + Al*Bh), out fp32 + bfc
template<int MODE>
__global__ __launch_bounds__(256) void gemm_bt(
        const bf16s* __restrict__ A0, const bf16s* __restrict__ A1,
        const bf16s* __restrict__ B0, const bf16s* __restrict__ B1,
        const float* __restrict__ bias,
        bf16s* __restrict__ Qo, bf16s* __restrict__ Ko, bf16s* __restrict__ Vo,
        float* __restrict__ out) {
    const int NT  = (MODE == 0 ? NQKV / 128 : DIM / 128);
    const int NWG = (MTOT / 128) * NT;
    int bid = blockIdx.x;
    bid = (bid & 7) * (NWG / 8) + (bid >> 3);         // XCD swizzle (NWG%8==0)
    int nt = bid % NT, mt = bid / NT;
    int m0 = mt * 128, n0 = nt * 128;
    __shared__ bf16s As[128 * 64];
    __shared__ bf16s Bs[128 * 64];
    int t = threadIdx.x;
    int lane = t & 63, w = t >> 6;
    int wr = w >> 1, wc = w & 1;
    int lr = lane & 15, lg = lane >> 4;
    // staging geometry: thread t, issue i covers LDS elems [i*2048+t*8, +8)
    int sflat[4];
    size_t sgoff[4];
    #pragma unroll
    for (int i = 0; i < 4; ++i) {
        int flat = i * 2048 + t * 8;
        int r = flat >> 6, c = flat & 63;
        int csw = (((c >> 3) ^ (r & 7)) << 3);        // source-side swizzle
        sflat[i] = flat;
        sgoff[i] = (size_t)r * DIM + csw;             // + m0/n0*DIM + k0 later
    }
    const int xorv = (lr & 7) << 3;                   // read-side XOR (elems)
    f32x4 acc[4][4] = {};
    const int KI = (MODE == 0 ? DIM / 64 : 3 * DIM / 64);
    for (int it = 0; it < KI; ++it) {
        int seg = it / (DIM / 64);
        int k0  = (it % (DIM / 64)) * 64;
        const bf16s* Ap = A0;
        const bf16s* Bp = B0;
        if (MODE == 1) {
            Ap = (seg == 2) ? A1 : A0;
            Bp = (seg == 1) ? B1 : B0;
        }
        #pragma unroll
        for (int i = 0; i < 4; ++i) {
            __builtin_amdgcn_global_load_lds(
                (g_u32*)(Ap + (size_t)m0 * DIM + k0 + sgoff[i]),
                (lds_u32*)&As[sflat[i]], 16, 0, 0);
            __builtin_amdgcn_global_load_lds(
                (g_u32*)(Bp + (size_t)n0 * DIM + k0 + sgoff[i]),
                (lds_u32*)&Bs[sflat[i]], 16, 0, 0);
        }
        __syncthreads();                               // vmcnt(0) drain + barrier
        #pragma unroll
        for (int kk = 0; kk < 2; ++kk) {
            bf16x8 af[4], bfr[4];
            #pragma unroll
            for (int i = 0; i < 4; ++i) {
                int arow = wr*64 + i*16 + lr;
                int brow = wc*64 + i*16 + lr;
                af[i]  = *(const bf16x8*)&As[arow*64 + ((kk*32 + lg*8) ^ xorv)];
                bfr[i] = *(const bf16x8*)&Bs[brow*64 + ((kk*32 + lg*8) ^ xorv)];
            }
            #pragma unroll
            for (int mi = 0; mi < 4; ++mi)
                #pragma unroll
                for (int ni = 0; ni < 4; ++ni)
                    acc[mi][ni] = __builtin_amdgcn_mfma_f32_16x16x32_bf16(
                        af[mi], bfr[ni], acc[mi][ni], 0, 0, 0);
        }
        __syncthreads();
    }
    if (MODE == 0) {
        #pragma unroll
        for (int mi = 0; mi < 4; ++mi) {
            int m_base = m0 + wr*64 + mi*16 + lg*4;
            int b = m_base >> 11, p = m_base & 2047;
            #pragma unroll
            for (int ni = 0; ni < 4; ++ni) {
                int n = n0 + wc*64 + ni*16 + lr;
                int which = n / DIM, within = n % DIM;
                int hh = within >> 6, d = within & 63;
                if (which == 2) {
                    float bb = bias[within];
                    uint2 pk;
                    pk.x = cvt_pk_bf16(acc[mi][ni][0] + bb, acc[mi][ni][1] + bb);
                    pk.y = cvt_pk_bf16(acc[mi][ni][2] + bb, acc[mi][ni][3] + bb);
                    *(uint2*)&Vo[(((size_t)(b*HEADS + hh))*HD + d)*PP + p] = pk;
                } else {
                    bf16s* dst = (which == 1) ? Ko : Qo;
                    #pragma unroll
                    for (int r = 0; r < 4; ++r)
                        dst[(((size_t)(b*HEADS + hh))*PP + p + r)*HD + d] =
                            f2bf(acc[mi][ni][r]);
                }
            }
        }
    } else {
        #pragma unroll
        for (int mi = 0; mi < 4; ++mi)
            #pragma unroll
            for (int ni = 0; ni < 4; ++ni)
                #pragma unroll
                for (int r = 0; r < 4; ++r) {
                    int m = m0 + wr*64 + mi*16 + lg*4 + r;
                    int n = n0 + wc*64 + ni*16 + lr;
                    out[(size_t)m * DIM + n] = acc[mi][ni][r] + bias[n];
                }
    }
}

// ------------------------------------------------------------ attention
// one block = one (b,h,qtile-of-128); 4 waves x 32 q-rows (2 subtiles of 16)
// swapped QK^T (lane owns one q per subtile); Q pre-scaled by 0.125*log2e;
// double-buffered K/V (register prefetch); defer-max; static-index diag mask;
// V fragments hoisted to regs; per-wave LDS P round-trip with
// lgkmcnt(0)+sched_barrier (no __syncthreads); ONE barrier per iter.
__global__ __launch_bounds__(256, 3) void attn_kernel(
        const bf16s* __restrict__ Q, const bf16s* __restrict__ K,
        const bf16s* __restrict__ Vt,
        bf16s* __restrict__ Oh, bf16s* __restrict__ Ol) {
    const int NWG = BB * HEADS * (PP / QBLK);        // 768
    int orig = blockIdx.x;
    int wg = (orig & 7) * (NWG / 8) + (orig >> 3);   // XCD swizzle
    int qt  = wg & 15;
    int tmp = wg >> 4;
    int h   = tmp % HEADS;
    int b   = tmp / HEADS;
    const size_t headoff = ((size_t)(b * HEADS + h)) * PP * HD;
    const bf16s* Qh = Q  + headoff;
    const bf16s* Kh = K  + headoff;
    const bf16s* Vh = Vt + headoff;                  // [d][p]
    __shared__ bf16s Ks[2][64][72];
    __shared__ bf16s Vs[2][64][72];                  // rows = d, cols = kv
    __shared__ bf16s Ps[4][16][72];                  // per-wave P [q_local][kv]
    int t = threadIdx.x, lane = t & 63, w = t >> 6;
    int lr = lane & 15, lg = lane >> 4;
    int q0  = qt * QBLK;
    int qw0 = q0 + w * 32;                           // wave's 32 q rows
    bf16x8 qf[2][2];
    #pragma unroll
    for (int u = 0; u < 2; ++u) {
        qf[u][0] = *(const bf16x8*)&Qh[(size_t)(qw0 + 16*u + lr) * HD + lg*8];
        qf[u][1] = *(const bf16x8*)&Qh[(size_t)(qw0 + 16*u + lr) * HD + 32 + lg*8];
    }
    float m_run[2] = {-1e30f, -1e30f};
    float l_run[2] = {0.f, 0.f};
    f32x4 o[2][4] = {};
    // staging geometry (fixed per thread)
    int sr[2], sc[2];
    uint4 kreg[2], vreg[2];
    #pragma unroll
    for (int i = 0; i < 2; ++i) {
        int flat = i * 2048 + t * 8;
        sr[i] = flat >> 6; sc[i] = flat & 63;
        kreg[i] = *(const uint4*)&Kh[(size_t)sr[i] * HD + sc[i]];
        vreg[i] = *(const uint4*)&Vh[(size_t)sr[i] * PP + sc[i]];
    }
    #pragma unroll
    for (int i = 0; i < 2; ++i) {
        *(uint4*)&Ks[0][sr[i]][sc[i]] = kreg[i];
        *(uint4*)&Vs[0][sr[i]][sc[i]] = vreg[i];
    }
    __syncthreads();
    for (int j = 0; j < 32; ++j) {
        int cur = j & 1;
        if (j < 31) {                                // prefetch next tile -> regs
            #pragma unroll
            for (int i = 0; i < 2; ++i) {
                kreg[i] = *(const uint4*)&Kh[(size_t)((j+1)*64 + sr[i]) * HD + sc[i]];
                vreg[i] = *(const uint4*)&Vh[(size_t)sr[i] * PP + (j+1)*64 + sc[i]];
            }
        }
        // ---- QK^T (scores pre-scaled via Wq; exp2 domain)
        f32x4 s[2][4] = {};
        #pragma unroll
        for (int kk = 0; kk < 2; ++kk) {
            bf16x8 kf[4];
            #pragma unroll
            for (int n = 0; n < 4; ++n)
                kf[n] = *(const bf16x8*)&Ks[cur][n*16 + lr][kk*32 + lg*8];
            #pragma unroll
            for (int u = 0; u < 2; ++u)
                #pragma unroll
                for (int n = 0; n < 4; ++n)
                    s[u][n] = __builtin_amdgcn_mfma_f32_16x16x32_bf16(
                        kf[n], qf[u][kk], s[u][n], 0, 0, 0);
        }
        // ---- diagonal mask: wave-uniform guard + STATIC indices (stays in regs)
        #pragma unroll
        for (int u = 0; u < 2; ++u) {
            if (((qw0 + 16*u) >> 6) == j) {
                int qrel = qw0 + 16*u + lr - j*64;   // lane's q within this kv tile
                #pragma unroll
                for (int n = 0; n < 4; ++n)
                    #pragma unroll
                    for (int r = 0; r < 4; ++r)
                        if (n*16 + lg*4 + r == qrel) s[u][n][r] = -1e30f;
            }
        }
        // ---- V fragments -> regs once per iter (shared by both subtiles)
        bf16x8 vfreg[2][4];
        #pragma unroll
        for (int kk = 0; kk < 2; ++kk)
            #pragma unroll
            for (int nd = 0; nd < 4; ++nd)
                vfreg[kk][nd] = *(const bf16x8*)&Vs[cur][nd*16 + lr][kk*32 + lg*8];
        // ---- softmax + per-wave LDS P round-trip + PV per subtile
        #pragma unroll
        for (int u = 0; u < 2; ++u) {
            float mt = -1e30f;
            #pragma unroll
            for (int n = 0; n < 4; ++n)
                #pragma unroll
                for (int r = 0; r < 4; ++r) mt = fmaxf(mt, s[u][n][r]);
            mt = fmaxf(mt, __shfl_xor(mt, 16));
            mt = fmaxf(mt, __shfl_xor(mt, 32));
            if (!__all(mt <= m_run[u] + 8.f)) {      // defer-max rescale
                float mn = fmaxf(m_run[u], mt);
                float corr = exp2g(m_run[u] - mn);
                m_run[u] = mn;
                l_run[u] *= corr;
                #pragma unroll
                for (int r = 0; r < 4; ++r) {
                    float cq = __shfl(corr, lg*4 + r);
                    #pragma unroll
                    for (int nd = 0; nd < 4; ++nd) o[u][nd][r] *= cq;
                }
            }
            float rs = 0.f;
            #pragma unroll
            for (int n = 0; n < 4; ++n)
                #pragma unroll
                for (int r = 0; r < 4; ++r) {
                    float p = exp2g(s[u][n][r] - m_run[u]);
                    s[u][n][r] = p;
                    rs += p;
                }
            rs += __shfl_xor(rs, 16);
            rs += __shfl_xor(rs, 32);
            l_run[u] += rs;
            // P -> per-wave LDS: lane holds P[q=lr][kv=n*16+lg*4+r]
            #pragma unroll
            for (int n = 0; n < 4; ++n) {
                uint2 pk;
                pk.x = cvt_pk_bf16(s[u][n][0], s[u][n][1]);
                pk.y = cvt_pk_bf16(s[u][n][2], s[u][n][3]);
                *(uint2*)&Ps[w][lr][n*16 + lg*4] = pk;
            }
            // same-wave DS is in-order; force compiler ordering + drain
            asm volatile("s_waitcnt lgkmcnt(0)" ::: "memory");
            __builtin_amdgcn_sched_barrier(0);
            #pragma unroll
            for (int kk = 0; kk < 2; ++kk) {
                bf16x8 pf = *(const bf16x8*)&Ps[w][lr][kk*32 + lg*8];
                #pragma unroll
                for (int nd = 0; nd < 4; ++nd)
                    o[u][nd] = __builtin_amdgcn_mfma_f32_16x16x32_bf16(
                        pf, vfreg[kk][nd], o[u][nd], 0, 0, 0);
            }
        }
        if (j < 31) {                                // publish next tile
            #pragma unroll
            for (int i = 0; i < 2; ++i) {
                *(uint4*)&Ks[cur ^ 1][sr[i]][sc[i]] = kreg[i];
                *(uint4*)&Vs[cur ^ 1][sr[i]][sc[i]] = vreg[i];
            }
            __syncthreads();                         // one full barrier per iter
        }
    }
    float invl[2][4];
    #pragma unroll
    for (int u = 0; u < 2; ++u)
        #pragma unroll
        for (int r = 0; r < 4; ++r)
            invl[u][r] = 1.0f / __shfl(l_run[u], lg*4 + r);
    #pragma unroll
    for (int u = 0; u < 2; ++u)
        #pragma unroll
        for (int nd = 0; nd < 4; ++nd)
            #pragma unroll
            for (int r = 0; r < 4; ++r) {
                int q = qw0 + 16*u + lg*4 + r;
                int d = nd*16 + lr;
                float v = o[u][nd][r] * invl[u][r];
                size_t idx = ((size_t)b * PP + q) * DIM + h * HD + d;
                bf16s hi = f2bf(v);
                Oh[idx] = hi;
                Ol[idx] = f2bf(v - bf2f(hi));
            }
}

// ---------------------------------------------------------------- launch
extern "C" void kernel_launch(void* const* d_in, const int* in_sizes, int n_in,
                              void* d_out, int out_size, void* d_ws, size_t ws_size,
                              hipStream_t stream) {
    const float* x    = (const float*)d_in[0];
    const float* ln_w = (const float*)d_in[1];
    const float* ln_b = (const float*)d_in[2];
    const float* Wq   = (const float*)d_in[3];
    const float* Wk   = (const float*)d_in[4];
    const float* Wv   = (const float*)d_in[5];
    const float* bv   = (const float*)d_in[6];
    const float* Wfc  = (const float*)d_in[7];
    const float* bfc  = (const float*)d_in[8];
    float* out = (float*)d_out;

    char* ws = (char*)d_ws;
    size_t off = 0;
    auto alloc = [&](size_t bytes) {
        void* p = ws + off;
        off += (bytes + 255) & ~(size_t)255;
        return p;
    };
    bf16s* xn     = (bf16s*)alloc((size_t)MTOT * DIM * 2);
    bf16s* Wqkv_t = (bf16s*)alloc((size_t)NQKV * DIM * 2);
    bf16s* Wfc_h  = (bf16s*)alloc((size_t)DIM * DIM * 2);
    bf16s* Wfc_l  = (bf16s*)alloc((size_t)DIM * DIM * 2);
    bf16s* Qb     = (bf16s*)alloc((size_t)MTOT * DIM * 2);
    bf16s* Kb     = (bf16s*)alloc((size_t)MTOT * DIM * 2);
    bf16s* Vtg    = (bf16s*)alloc((size_t)MTOT * DIM * 2);   // V^T [b,h,d,p]
    bf16s* Ah     = (bf16s*)alloc((size_t)MTOT * DIM * 2);
    bf16s* Al     = (bf16s*)alloc((size_t)MTOT * DIM * 2);

    const float SC = 0.125f * 1.44269504f;   // softmax scale * log2(e), folded into Wq

    ln_kernel<<<MTOT, 256, 0, stream>>>(x, ln_w, ln_b, xn);

    dim3 tb(32, 8);
    transpose_cast<false><<<dim3(24, 24), tb, 0, stream>>>(Wq, Wqkv_t,                 nullptr, DIM, DIM, SC);
    transpose_cast<false><<<dim3(24, 24), tb, 0, stream>>>(Wk, Wqkv_t + 768 * 768,     nullptr, DIM, DIM, 1.0f);
    transpose_cast<false><<<dim3(24, 24), tb, 0, stream>>>(Wv, Wqkv_t + 2 * 768 * 768, nullptr, DIM, DIM, 1.0f);
    transpose_cast<true ><<<dim3(24, 24), tb, 0, stream>>>(Wfc, Wfc_h, Wfc_l, DIM, DIM, 1.0f);

    gemm_bt<0><<<(MTOT / 128) * (NQKV / 128), 256, 0, stream>>>(
        xn, nullptr, Wqkv_t, nullptr, bv, Qb, Kb, Vtg, nullptr);

    attn_kernel<<<BB * HEADS * (PP / QBLK), 256, 0, stream>>>(Qb, Kb, Vtg, Ah, Al);

    gemm_bt<1><<<(MTOT / 128) * (DIM / 128), 256, 0, stream>>>(
        Ah, Al, Wfc_h, Wfc_l, bfc, nullptr, nullptr, nullptr, out);
}

// Round 12
// 185.764 us; speedup vs baseline: 2.3226x; 1.0930x over previous
//
#include <hip/hip_runtime.h>

#define DIM    768
#define HEADS  12
#define HD     64
#define BB     4
#define PP     2048
#define MTOT   8192   /* BB*PP */
#define NQKV   2304
#define QBLK   128

typedef unsigned short bf16s;                                   // bf16 storage
typedef short bf16x8 __attribute__((ext_vector_type(8)));       // MFMA A/B frag
typedef float f32x4  __attribute__((ext_vector_type(4)));       // MFMA C/D frag

typedef const __attribute__((address_space(1))) unsigned int g_u32;
typedef __attribute__((address_space(3))) unsigned int lds_u32;

__device__ __forceinline__ bf16s f2bf(float f) {
    unsigned int u = __float_as_uint(f);
    unsigned int r = u + 0x7fffu + ((u >> 16) & 1u);            // RNE
    return (bf16s)(r >> 16);
}
__device__ __forceinline__ float bf2f(bf16s s) {
    return __uint_as_float(((unsigned int)s) << 16);
}
__device__ __forceinline__ float exp2g(float x) {
    return __builtin_amdgcn_exp2f(x);                           // v_exp_f32
}
__device__ __forceinline__ unsigned cvt_pk_bf16(float a, float b) {
    unsigned r;
    asm("v_cvt_pk_bf16_f32 %0, %1, %2" : "=v"(r) : "v"(a), "v"(b));
    return r;                                                   // lo=bf16(a), hi=bf16(b)
}

// ---------------------------------------------------------------- LayerNorm
__global__ __launch_bounds__(256) void ln_kernel(
        const float* __restrict__ x, const float* __restrict__ w,
        const float* __restrict__ b, bf16s* __restrict__ xn) {
    int row = blockIdx.x;
    const float* xr = x + (size_t)row * DIM;
    int t = threadIdx.x;
    float v0 = xr[t], v1 = xr[t + 256], v2 = xr[t + 512];
    float s  = v0 + v1 + v2;
    float ss = v0*v0 + v1*v1 + v2*v2;
    for (int off = 32; off; off >>= 1) {
        s  += __shfl_down(s, off);
        ss += __shfl_down(ss, off);
    }
    __shared__ float red[8];
    int wid = t >> 6, lane = t & 63;
    if (lane == 0) { red[wid] = s; red[4 + wid] = ss; }
    __syncthreads();
    if (t == 0) {
        float S  = red[0] + red[1] + red[2] + red[3];
        float SS = red[4] + red[5] + red[6] + red[7];
        float mean = S * (1.0f / DIM);
        float var  = SS * (1.0f / DIM) - mean * mean;
        red[0] = mean;
        red[1] = rsqrtf(var + 1e-5f);
    }
    __syncthreads();
    float mean = red[0], inv = red[1];
    bf16s* xo = xn + (size_t)row * DIM;
    xo[t]       = f2bf((v0 - mean) * inv * w[t]       + b[t]);
    xo[t + 256] = f2bf((v1 - mean) * inv * w[t + 256] + b[t + 256]);
    xo[t + 512] = f2bf((v2 - mean) * inv * w[t + 512] + b[t + 512]);
}

// ------------------------------------------------- transpose + cast weights
// one launch, grid.z selects: 0=Wq(*sc) 1=Wk 2=Wv -> Wqkv_t; 3=Wfc -> hi+lo
__global__ __launch_bounds__(256) void transpose_all(
        const float* __restrict__ Wq, const float* __restrict__ Wk,
        const float* __restrict__ Wv, const float* __restrict__ Wfc,
        bf16s* __restrict__ Wqkv_t, bf16s* __restrict__ Wfc_h,
        bf16s* __restrict__ Wfc_l, float sc) {
    int z = blockIdx.z;
    const float* src = (z == 0) ? Wq : (z == 1) ? Wk : (z == 2) ? Wv : Wfc;
    float scale = (z == 0) ? sc : 1.0f;
    __shared__ float tile[32][33];
    int n0 = blockIdx.x * 32, k0 = blockIdx.y * 32;
    int tx = threadIdx.x, ty = threadIdx.y;
    #pragma unroll
    for (int i = 0; i < 4; ++i)
        tile[ty + 8*i][tx] = src[(size_t)(k0 + ty + 8*i) * DIM + n0 + tx];
    __syncthreads();
    #pragma unroll
    for (int i = 0; i < 4; ++i) {
        float v = tile[tx][ty + 8*i] * scale;
        size_t oidx = (size_t)(n0 + ty + 8*i) * DIM + k0 + tx;
        bf16s hi = f2bf(v);
        if (z < 3) {
            Wqkv_t[(size_t)z * DIM * DIM + oidx] = hi;
        } else {
            Wfc_h[oidx] = hi;
            Wfc_l[oidx] = f2bf(v - bf2f(hi));
        }
    }
}

// ----------------------------------------------------------------- GEMM
// C[M x N] = A[M x 768(K)] @ Bt[N x 768]^T ; 4 waves
// MODE 0: 128x128 tile (2x2 waves of 64x64), N=2304 -> Q/K [b,h,p,d], V^T (+bv)
// MODE 1: 128x64 tile (2x2 waves of 64x32), N=768, K'=3*768 split, fp32 out + bfc
// Staging: global_load_lds width=16, linear LDS, source-XOR swizzle + read-XOR.
template<int MODE>
__global__ __launch_bounds__(256) void gemm_bt(
        const bf16s* __restrict__ A0, const bf16s* __restrict__ A1,
        const bf16s* __restrict__ B0, const bf16s* __restrict__ B1,
        const float* __restrict__ bias,
        bf16s* __restrict__ Qo, bf16s* __restrict__ Ko, bf16s* __restrict__ Vo,
        float* __restrict__ out) {
    const int BN   = (MODE == 0 ? 128 : 64);
    const int NI   = (MODE == 0 ? 4 : 2);             // B frags per wave
    const int BISS = (MODE == 0 ? 4 : 2);             // B staging issues
    const int NT   = (MODE == 0 ? NQKV / 128 : DIM / 64);
    const int NWG  = (MTOT / 128) * NT;
    int bid = blockIdx.x;
    bid = (bid & 7) * (NWG / 8) + (bid >> 3);         // XCD swizzle (NWG%8==0)
    int nt = bid % NT, mt = bid / NT;
    int m0 = mt * 128, n0 = nt * BN;
    __shared__ bf16s As[128 * 64];
    __shared__ bf16s Bs[BN * 64];
    int t = threadIdx.x;
    int lane = t & 63, w = t >> 6;
    int wr = w >> 1, wc = w & 1;
    int lr = lane & 15, lg = lane >> 4;
    // staging geometry: thread t, issue i covers LDS elems [i*2048+t*8, +8)
    int sflat[4];
    size_t sgoff[4];
    #pragma unroll
    for (int i = 0; i < 4; ++i) {
        int flat = i * 2048 + t * 8;
        int r = flat >> 6, c = flat & 63;
        int csw = (((c >> 3) ^ (r & 7)) << 3);        // source-side swizzle
        sflat[i] = flat;
        sgoff[i] = (size_t)r * DIM + csw;             // + m0/n0*DIM + k0 later
    }
    const int xorv = (lr & 7) << 3;                   // read-side XOR (elems)
    f32x4 acc[4][NI] = {};
    const int KI = (MODE == 0 ? DIM / 64 : 3 * DIM / 64);
    for (int it = 0; it < KI; ++it) {
        int seg = it / (DIM / 64);
        int k0  = (it % (DIM / 64)) * 64;
        const bf16s* Ap = A0;
        const bf16s* Bp = B0;
        if (MODE == 1) {
            Ap = (seg == 2) ? A1 : A0;
            Bp = (seg == 1) ? B1 : B0;
        }
        #pragma unroll
        for (int i = 0; i < 4; ++i)
            __builtin_amdgcn_global_load_lds(
                (g_u32*)(Ap + (size_t)m0 * DIM + k0 + sgoff[i]),
                (lds_u32*)&As[sflat[i]], 16, 0, 0);
        #pragma unroll
        for (int i = 0; i < BISS; ++i)
            __builtin_amdgcn_global_load_lds(
                (g_u32*)(Bp + (size_t)n0 * DIM + k0 + sgoff[i]),
                (lds_u32*)&Bs[sflat[i]], 16, 0, 0);
        __syncthreads();                               // vmcnt(0) drain + barrier
        #pragma unroll
        for (int kk = 0; kk < 2; ++kk) {
            bf16x8 af[4], bfr[NI];
            #pragma unroll
            for (int i = 0; i < 4; ++i) {
                int arow = wr*64 + i*16 + lr;
                af[i] = *(const bf16x8*)&As[arow*64 + ((kk*32 + lg*8) ^ xorv)];
            }
            #pragma unroll
            for (int i = 0; i < NI; ++i) {
                int brow = wc*(BN/2) + i*16 + lr;
                bfr[i] = *(const bf16x8*)&Bs[brow*64 + ((kk*32 + lg*8) ^ xorv)];
            }
            #pragma unroll
            for (int mi = 0; mi < 4; ++mi)
                #pragma unroll
                for (int ni = 0; ni < NI; ++ni)
                    acc[mi][ni] = __builtin_amdgcn_mfma_f32_16x16x32_bf16(
                        af[mi], bfr[ni], acc[mi][ni], 0, 0, 0);
        }
        __syncthreads();
    }
    if (MODE == 0) {
        #pragma unroll
        for (int mi = 0; mi < 4; ++mi) {
            int m_base = m0 + wr*64 + mi*16 + lg*4;
            int b = m_base >> 11, p = m_base & 2047;
            #pragma unroll
            for (int ni = 0; ni < NI; ++ni) {
                int n = n0 + wc*64 + ni*16 + lr;
                int which = n / DIM, within = n % DIM;
                int hh = within >> 6, d = within & 63;
                if (which == 2) {
                    float bb = bias[within];
                    uint2 pk;
                    pk.x = cvt_pk_bf16(acc[mi][ni][0] + bb, acc[mi][ni][1] + bb);
                    pk.y = cvt_pk_bf16(acc[mi][ni][2] + bb, acc[mi][ni][3] + bb);
                    *(uint2*)&Vo[(((size_t)(b*HEADS + hh))*HD + d)*PP + p] = pk;
                } else {
                    bf16s* dst = (which == 1) ? Ko : Qo;
                    #pragma unroll
                    for (int r = 0; r < 4; ++r)
                        dst[(((size_t)(b*HEADS + hh))*PP + p + r)*HD + d] =
                            f2bf(acc[mi][ni][r]);
                }
            }
        }
    } else {
        #pragma unroll
        for (int mi = 0; mi < 4; ++mi)
            #pragma unroll
            for (int ni = 0; ni < NI; ++ni)
                #pragma unroll
                for (int r = 0; r < 4; ++r) {
                    int m = m0 + wr*64 + mi*16 + lg*4 + r;
                    int n = n0 + wc*32 + ni*16 + lr;
                    out[(size_t)m * DIM + n] = acc[mi][ni][r] + bias[n];
                }
    }
}

// ------------------------------------------------------------ attention
// one block = one (b,h,qtile-of-128); 4 waves x 32 q-rows (2 subtiles of 16)
// swapped QK^T; Q pre-scaled by 0.125*log2e; defer-max; static-index diag mask;
// K/V staged via global_load_lds (linear LDS, source-XOR swizzle, read-XOR);
// double-buffered, ONE barrier per iter; per-wave Ps (swizzled) round-trip
// with lgkmcnt(0)+sched_barrier (same-wave DS in-order, no block barrier).
__global__ __launch_bounds__(256, 3) void attn_kernel(
        const bf16s* __restrict__ Q, const bf16s* __restrict__ K,
        const bf16s* __restrict__ Vt,
        bf16s* __restrict__ Oh, bf16s* __restrict__ Ol) {
    const int NWG = BB * HEADS * (PP / QBLK);        // 768
    int orig = blockIdx.x;
    int wg = (orig & 7) * (NWG / 8) + (orig >> 3);   // XCD swizzle
    int qt  = wg & 15;
    int tmp = wg >> 4;
    int h   = tmp % HEADS;
    int b   = tmp / HEADS;
    const size_t headoff = ((size_t)(b * HEADS + h)) * PP * HD;
    const bf16s* Qh = Q  + headoff;
    const bf16s* Kh = K  + headoff;
    const bf16s* Vh = Vt + headoff;                  // [d][p]
    __shared__ bf16s Ks[2][64 * 64];                 // linear, swizzled
    __shared__ bf16s Vs[2][64 * 64];                 // rows = d, cols = kv
    __shared__ bf16s Ps[4][16 * 64];                 // per-wave P, swizzled
    int t = threadIdx.x, lane = t & 63, w = t >> 6;
    int lr = lane & 15, lg = lane >> 4;
    int q0  = qt * QBLK;
    int qw0 = q0 + w * 32;                           // wave's 32 q rows
    const int xorv = (lr & 7) << 3;                  // read-side XOR (elems)
    bf16x8 qf[2][2];
    #pragma unroll
    for (int u = 0; u < 2; ++u) {
        qf[u][0] = *(const bf16x8*)&Qh[(size_t)(qw0 + 16*u + lr) * HD + lg*8];
        qf[u][1] = *(const bf16x8*)&Qh[(size_t)(qw0 + 16*u + lr) * HD + 32 + lg*8];
    }
    float m_run[2] = {-1e30f, -1e30f};
    float l_run[2] = {0.f, 0.f};
    f32x4 o[2][4] = {};
    // staging geometry: thread t, issue i covers LDS elems [i*2048+t*8, +8)
    int sflat[2];
    size_t skoff[2], svoff[2];
    #pragma unroll
    for (int i = 0; i < 2; ++i) {
        int flat = i * 2048 + t * 8;
        int r = flat >> 6, c = flat & 63;
        int csw = (((c >> 3) ^ (r & 7)) << 3);       // source-side swizzle
        sflat[i] = flat;
        skoff[i] = (size_t)r * HD + csw;             // + j*64*HD per tile
        svoff[i] = (size_t)r * PP + csw;             // + j*64 per tile
    }
    #pragma unroll
    for (int i = 0; i < 2; ++i) {
        __builtin_amdgcn_global_load_lds((g_u32*)(Kh + skoff[i]),
                                         (lds_u32*)&Ks[0][sflat[i]], 16, 0, 0);
        __builtin_amdgcn_global_load_lds((g_u32*)(Vh + svoff[i]),
                                         (lds_u32*)&Vs[0][sflat[i]], 16, 0, 0);
    }
    __syncthreads();
    for (int j = 0; j < 32; ++j) {
        int cur = j & 1;
        if (j < 31) {                                // prefetch next tile -> LDS
            #pragma unroll
            for (int i = 0; i < 2; ++i) {
                __builtin_amdgcn_global_load_lds(
                    (g_u32*)(Kh + (size_t)(j+1)*64*HD + skoff[i]),
                    (lds_u32*)&Ks[cur ^ 1][sflat[i]], 16, 0, 0);
                __builtin_amdgcn_global_load_lds(
                    (g_u32*)(Vh + svoff[i] + (j+1)*64),
                    (lds_u32*)&Vs[cur ^ 1][sflat[i]], 16, 0, 0);
            }
        }
        // ---- QK^T (scores pre-scaled via Wq; exp2 domain)
        f32x4 s[2][4] = {};
        #pragma unroll
        for (int kk = 0; kk < 2; ++kk) {
            bf16x8 kf[4];
            #pragma unroll
            for (int n = 0; n < 4; ++n)
                kf[n] = *(const bf16x8*)&Ks[cur][(n*16 + lr)*64 + ((kk*32 + lg*8) ^ xorv)];
            #pragma unroll
            for (int u = 0; u < 2; ++u)
                #pragma unroll
                for (int n = 0; n < 4; ++n)
                    s[u][n] = __builtin_amdgcn_mfma_f32_16x16x32_bf16(
                        kf[n], qf[u][kk], s[u][n], 0, 0, 0);
        }
        // ---- diagonal mask: wave-uniform guard + STATIC indices
        #pragma unroll
        for (int u = 0; u < 2; ++u) {
            if (((qw0 + 16*u) >> 6) == j) {
                int qrel = qw0 + 16*u + lr - j*64;   // lane's q within this kv tile
                #pragma unroll
                for (int n = 0; n < 4; ++n)
                    #pragma unroll
                    for (int r = 0; r < 4; ++r)
                        if (n*16 + lg*4 + r == qrel) s[u][n][r] = -1e30f;
            }
        }
        // ---- V fragments -> regs once per iter (shared by both subtiles)
        bf16x8 vfreg[2][4];
        #pragma unroll
        for (int kk = 0; kk < 2; ++kk)
            #pragma unroll
            for (int nd = 0; nd < 4; ++nd)
                vfreg[kk][nd] = *(const bf16x8*)&Vs[cur][(nd*16 + lr)*64 + ((kk*32 + lg*8) ^ xorv)];
        // ---- softmax + per-wave LDS P round-trip + PV per subtile
        #pragma unroll
        for (int u = 0; u < 2; ++u) {
            float mt = -1e30f;
            #pragma unroll
            for (int n = 0; n < 4; ++n)
                #pragma unroll
                for (int r = 0; r < 4; ++r) mt = fmaxf(mt, s[u][n][r]);
            mt = fmaxf(mt, __shfl_xor(mt, 16));
            mt = fmaxf(mt, __shfl_xor(mt, 32));
            if (!__all(mt <= m_run[u] + 8.f)) {      // defer-max rescale
                float mn = fmaxf(m_run[u], mt);
                float corr = exp2g(m_run[u] - mn);
                m_run[u] = mn;
                l_run[u] *= corr;
                #pragma unroll
                for (int r = 0; r < 4; ++r) {
                    float cq = __shfl(corr, lg*4 + r);
                    #pragma unroll
                    for (int nd = 0; nd < 4; ++nd) o[u][nd][r] *= cq;
                }
            }
            float rs = 0.f;
            #pragma unroll
            for (int n = 0; n < 4; ++n)
                #pragma unroll
                for (int r = 0; r < 4; ++r) {
                    float p = exp2g(s[u][n][r] - m_run[u]);
                    s[u][n][r] = p;
                    rs += p;
                }
            rs += __shfl_xor(rs, 16);
            rs += __shfl_xor(rs, 32);
            l_run[u] += rs;
            // P -> per-wave LDS (swizzled): lane holds P[q=lr][kv=n*16+lg*4+r]
            #pragma unroll
            for (int n = 0; n < 4; ++n) {
                uint2 pk;
                pk.x = cvt_pk_bf16(s[u][n][0], s[u][n][1]);
                pk.y = cvt_pk_bf16(s[u][n][2], s[u][n][3]);
                *(uint2*)&Ps[w][lr*64 + ((n*16 + lg*4) ^ xorv)] = pk;
            }
            // same-wave DS is in-order; force compiler ordering + drain
            asm volatile("s_waitcnt lgkmcnt(0)" ::: "memory");
            __builtin_amdgcn_sched_barrier(0);
            #pragma unroll
            for (int kk = 0; kk < 2; ++kk) {
                bf16x8 pf = *(const bf16x8*)&Ps[w][lr*64 + ((kk*32 + lg*8) ^ xorv)];
                #pragma unroll
                for (int nd = 0; nd < 4; ++nd)
                    o[u][nd] = __builtin_amdgcn_mfma_f32_16x16x32_bf16(
                        pf, vfreg[kk][nd], o[u][nd], 0, 0, 0);
            }
        }
        if (j < 31)
            __syncthreads();                         // one barrier: drains prefetch,
                                                     // syncs dbuf handoff
    }
    float invl[2][4];
    #pragma unroll
    for (int u = 0; u < 2; ++u)
        #pragma unroll
        for (int r = 0; r < 4; ++r)
            invl[u][r] = 1.0f / __shfl(l_run[u], lg*4 + r);
    #pragma unroll
    for (int u = 0; u < 2; ++u)
        #pragma unroll
        for (int nd = 0; nd < 4; ++nd)
            #pragma unroll
            for (int r = 0; r < 4; ++r) {
                int q = qw0 + 16*u + lg*4 + r;
                int d = nd*16 + lr;
                float v = o[u][nd][r] * invl[u][r];
                size_t idx = ((size_t)b * PP + q) * DIM + h * HD + d;
                bf16s hi = f2bf(v);
                Oh[idx] = hi;
                Ol[idx] = f2bf(v - bf2f(hi));
            }
}

// ---------------------------------------------------------------- launch
extern "C" void kernel_launch(void* const* d_in, const int* in_sizes, int n_in,
                              void* d_out, int out_size, void* d_ws, size_t ws_size,
                              hipStream_t stream) {
    const float* x    = (const float*)d_in[0];
    const float* ln_w = (const float*)d_in[1];
    const float* ln_b = (const float*)d_in[2];
    const float* Wq   = (const float*)d_in[3];
    const float* Wk   = (const float*)d_in[4];
    const float* Wv   = (const float*)d_in[5];
    const float* bv   = (const float*)d_in[6];
    const float* Wfc  = (const float*)d_in[7];
    const float* bfc  = (const float*)d_in[8];
    float* out = (float*)d_out;

    char* ws = (char*)d_ws;
    size_t off = 0;
    auto alloc = [&](size_t bytes) {
        void* p = ws + off;
        off += (bytes + 255) & ~(size_t)255;
        return p;
    };
    bf16s* xn     = (bf16s*)alloc((size_t)MTOT * DIM * 2);
    bf16s* Wqkv_t = (bf16s*)alloc((size_t)NQKV * DIM * 2);
    bf16s* Wfc_h  = (bf16s*)alloc((size_t)DIM * DIM * 2);
    bf16s* Wfc_l  = (bf16s*)alloc((size_t)DIM * DIM * 2);
    bf16s* Qb     = (bf16s*)alloc((size_t)MTOT * DIM * 2);
    bf16s* Kb     = (bf16s*)alloc((size_t)MTOT * DIM * 2);
    bf16s* Vtg    = (bf16s*)alloc((size_t)MTOT * DIM * 2);   // V^T [b,h,d,p]
    bf16s* Ah     = (bf16s*)alloc((size_t)MTOT * DIM * 2);
    bf16s* Al     = (bf16s*)alloc((size_t)MTOT * DIM * 2);

    const float SC = 0.125f * 1.44269504f;   // softmax scale * log2(e), folded into Wq

    ln_kernel<<<MTOT, 256, 0, stream>>>(x, ln_w, ln_b, xn);

    transpose_all<<<dim3(24, 24, 4), dim3(32, 8), 0, stream>>>(
        Wq, Wk, Wv, Wfc, Wqkv_t, Wfc_h, Wfc_l, SC);

    gemm_bt<0><<<(MTOT / 128) * (NQKV / 128), 256, 0, stream>>>(
        xn, nullptr, Wqkv_t, nullptr, bv, Qb, Kb, Vtg, nullptr);

    attn_kernel<<<BB * HEADS * (PP / QBLK), 256, 0, stream>>>(Qb, Kb, Vtg, Ah, Al);

    gemm_bt<1><<<(MTOT / 128) * (DIM / 64), 256, 0, stream>>>(
        Ah, Al, Wfc_h, Wfc_l, bfc, nullptr, nullptr, nullptr, out);
}